// Round 12
// baseline (2064.329 us; speedup 1.0000x reference)
//
#include <hip/hip_runtime.h>
#include <hip/hip_bf16.h>
#include <stdint.h>

#define LL 6
#define DD 1024
#define HH 16
#define DKK 64
#define SS 512
#define BB 8
#define DFF_ 4096
#define BS (BB*SS)
#define NEGV -1.0e9f

typedef __attribute__((ext_vector_type(8))) short short8;
typedef __attribute__((ext_vector_type(4))) float f32x4;
typedef __attribute__((ext_vector_type(4))) unsigned short ushort4v;

static __device__ __forceinline__ float bf2f(unsigned short u){
  union { unsigned int i; float f; } v; v.i = ((unsigned int)u)<<16; return v.f;
}
static __device__ __forceinline__ unsigned short f2bf(float f){
  union { float f; unsigned int i; } v; v.f=f;
  unsigned int r = v.i + 0x7fff + ((v.i>>16)&1);   // RNE
  return (unsigned short)(r>>16);
}

static __device__ __forceinline__ void gload16(const void* g, void* l){
  __builtin_amdgcn_global_load_lds((const __attribute__((address_space(1))) unsigned int*)g,
                                   (__attribute__((address_space(3))) unsigned int*)l, 16, 0, 0);
}

// ---------------- multi-descriptor fp32->bf16 transpose: out[c][r] = in[r][c] ----------------
struct TrDesc { const float* in; unsigned short* out; long is1,is2,os1,os2; int ldin,ldout,zd,gx,gy; };
struct TrPack { TrDesc d[7]; int cum[8]; };

__global__ void __launch_bounds__(256) tr_multi_k(TrPack P)
{
  __shared__ float t[32][33];
  int bid=blockIdx.x, di=0;
  #pragma unroll
  for(int k=1;k<7;k++) if(bid>=P.cum[k]) di=k;
  TrDesc dd=P.d[di];
  int local=bid-P.cum[di];
  int bx=local%dd.gx; int rest=local/dd.gx;
  int by=rest%dd.gy; int z=rest/dd.gy;
  int z1=z/dd.zd, z2=z%dd.zd;
  const float* ip=dd.in+z1*dd.is1+z2*dd.is2;
  unsigned short* op=dd.out+z1*dd.os1+z2*dd.os2;
  int r0=by*32, c0=bx*32;
  int tx=threadIdx.x, ty=threadIdx.y;
  #pragma unroll
  for(int i=0;i<4;i++)
    t[ty+i*8][tx] = ip[(long)(r0+ty+i*8)*dd.ldin + c0+tx];
  __syncthreads();
  #pragma unroll
  for(int i=0;i<4;i++)
    op[(long)(c0+ty+i*8)*dd.ldout + r0+tx] = f2bf(t[tx][ty+i*8]);
}

// ---------------- mask bit-pack ----------------
__global__ void __launch_bounds__(256) maskpack_k(const int* __restrict__ mask, unsigned* __restrict__ mb)
{
  int idx = blockIdx.x*256 + threadIdx.x;     // idx = row*16 + w
  int row = idx>>4, w = idx&15;
  const int* mp = mask + (long)row*SS + w*32;
  unsigned v=0;
  #pragma unroll
  for(int i=0;i<32;i++) v |= (mp[i]!=0) ? (1u<<i) : 0u;
  mb[idx]=v;
}

// ---------------- LayerNorm: out = LN(src)*g+b (+resid); fp32 and/or bf16 out ----------------
__global__ void __launch_bounds__(256) ln_k(const float* __restrict__ src,
    const float* __restrict__ gw, const float* __restrict__ bw,
    float* __restrict__ outf, unsigned short* __restrict__ outb,
    const float* __restrict__ resid)
{
  long row=blockIdx.x;
  float4 v=((const float4*)(src+row*DD))[threadIdx.x];
  float s=v.x+v.y+v.z+v.w;
  float s2=v.x*v.x+v.y*v.y+v.z*v.z+v.w*v.w;
  #pragma unroll
  for(int o=32;o;o>>=1){ s+=__shfl_xor(s,o); s2+=__shfl_xor(s2,o); }
  __shared__ float red[8];
  int wid=threadIdx.x>>6, lane=threadIdx.x&63;
  if(lane==0){ red[wid]=s; red[4+wid]=s2; }
  __syncthreads();
  s=red[0]+red[1]+red[2]+red[3];
  s2=red[4]+red[5]+red[6]+red[7];
  float mu=s*(1.f/DD);
  float rstd=rsqrtf(s2*(1.f/DD)-mu*mu+1e-5f);
  int c=threadIdx.x*4;
  float4 g4=*(const float4*)(gw+c), b4=*(const float4*)(bw+c);
  float4 o;
  o.x=(v.x-mu)*rstd*g4.x+b4.x;
  o.y=(v.y-mu)*rstd*g4.y+b4.y;
  o.z=(v.z-mu)*rstd*g4.z+b4.z;
  o.w=(v.w-mu)*rstd*g4.w+b4.w;
  if(resid){
    float4 r4=((const float4*)(resid+row*DD))[threadIdx.x];
    o.x+=r4.x; o.y+=r4.y; o.z+=r4.z; o.w+=r4.w;
  }
  if(outf) ((float4*)(outf+row*DD))[threadIdx.x]=o;
  if(outb){
    uint2 pk;
    pk.x=(unsigned)f2bf(o.x)|((unsigned)f2bf(o.y)<<16);
    pk.y=(unsigned)f2bf(o.z)|((unsigned)f2bf(o.w)<<16);
    ((uint2*)(outb+row*DD))[threadIdx.x]=pk;
  }
}

// ---------------- fused: t = LN(src;g2,b2)+resid -> outf;  LN(t;g1,b1) -> outb ----------------
__global__ void __launch_bounds__(256) ln2_k(const float* __restrict__ src,
    const float* __restrict__ resid,
    const float* __restrict__ g2, const float* __restrict__ b2,
    const float* __restrict__ g1, const float* __restrict__ b1,
    float* __restrict__ outf, unsigned short* __restrict__ outb)
{
  long row=blockIdx.x;
  int wid=threadIdx.x>>6, lane=threadIdx.x&63, c=threadIdx.x*4;
  __shared__ float red[8];
  float4 v=((const float4*)(src+row*DD))[threadIdx.x];
  float s=v.x+v.y+v.z+v.w;
  float s2=v.x*v.x+v.y*v.y+v.z*v.z+v.w*v.w;
  #pragma unroll
  for(int o=32;o;o>>=1){ s+=__shfl_xor(s,o); s2+=__shfl_xor(s2,o); }
  if(lane==0){ red[wid]=s; red[4+wid]=s2; }
  __syncthreads();
  s=red[0]+red[1]+red[2]+red[3];
  s2=red[4]+red[5]+red[6]+red[7];
  float mu=s*(1.f/DD);
  float rstd=rsqrtf(s2*(1.f/DD)-mu*mu+1e-5f);
  float4 g4=*(const float4*)(g2+c), b4=*(const float4*)(b2+c);
  float4 r4=((const float4*)(resid+row*DD))[threadIdx.x];
  float4 o;
  o.x=(v.x-mu)*rstd*g4.x+b4.x+r4.x;
  o.y=(v.y-mu)*rstd*g4.y+b4.y+r4.y;
  o.z=(v.z-mu)*rstd*g4.z+b4.z+r4.z;
  o.w=(v.w-mu)*rstd*g4.w+b4.w+r4.w;
  ((float4*)(outf+row*DD))[threadIdx.x]=o;
  s=o.x+o.y+o.z+o.w;
  s2=o.x*o.x+o.y*o.y+o.z*o.z+o.w*o.w;
  #pragma unroll
  for(int of=32;of;of>>=1){ s+=__shfl_xor(s,of); s2+=__shfl_xor(s2,of); }
  __syncthreads();
  if(lane==0){ red[wid]=s; red[4+wid]=s2; }
  __syncthreads();
  s=red[0]+red[1]+red[2]+red[3];
  s2=red[4]+red[5]+red[6]+red[7];
  mu=s*(1.f/DD);
  rstd=rsqrtf(s2*(1.f/DD)-mu*mu+1e-5f);
  g4=*(const float4*)(g1+c); b4=*(const float4*)(b1+c);
  uint2 pk;
  pk.x=(unsigned)f2bf((o.x-mu)*rstd*g4.x+b4.x)|((unsigned)f2bf((o.y-mu)*rstd*g4.y+b4.y)<<16);
  pk.y=(unsigned)f2bf((o.z-mu)*rstd*g4.z+b4.z)|((unsigned)f2bf((o.w-mu)*rstd*g4.w+b4.w)<<16);
  ((uint2*)(outb+row*DD))[threadIdx.x]=pk;
}

// ---------------- GEMM params ----------------
struct GemmP {
  const unsigned short* A; long sA1; int ldA;
  const unsigned short* B; long sB1; int ldB;
  float* outF; unsigned short* outB; long sO1; int ldO;
  const float* bias;
  const float* residF; int ldR;
  const unsigned short* residB;
  unsigned short *kt, *vt;
  int K, relu;
};

// ---------------- engine A v2: 128x128, 8 waves (wt 64x32), BK=64, 2 LDS buffers (64KB
//   -> 2 blocks/CU: cross-block barrier hiding), distance-1 issue-early staging,
//   __syncthreads full-drain (race-free), both-sides (row&7) swizzle, setprio ----------------
__global__ void __launch_bounds__(512,4) gemmA_k(GemmP p)
{
  constexpr int BM=128, BN=128, BK=64;
  constexpr int BUFE=(BM+BN)*BK;                 // 16384 elems (32 KB)
  constexpr int FN=2;
  constexpr int WNT=32;
  __shared__ __align__(16) unsigned short smem[2*BUFE];   // 64 KB -> 2 blocks/CU
  const int tid=threadIdx.x, lane=tid&63, wid=tid>>6;
  const int wr=wid>>2, wc=wid&3;
  const int lr=lane&15, lk=(lane>>4)*8;
  const int m0=blockIdx.y*BM, n0=blockIdx.x*BN;
  const int z=blockIdx.z;
  const unsigned short* Ap=p.A+(long)z*p.sA1;
  const unsigned short* Bp=p.B+(long)z*p.sB1;
  const int NT=p.K/BK;

  const int sr8 = lane>>3;
  const int scol = ((lane&7) ^ sr8) << 3;

  #define STAGEA(T,BI) { \
    const long kb_=(long)(T)*BK; \
    unsigned short* As_=smem+(BI)*BUFE; \
    unsigned short* Bs_=As_+BM*BK; \
    _Pragma("unroll") \
    for(int L=0;L<2;L++){ \
      int r_=L*64+wid*8+sr8; \
      gload16(Ap+(long)(m0+r_)*p.ldA+kb_+scol, As_+L*4096+wid*512); \
    } \
    _Pragma("unroll") \
    for(int L=0;L<2;L++){ \
      int r_=L*64+wid*8+sr8; \
      gload16(Bp+(long)(n0+r_)*p.ldB+kb_+scol, Bs_+L*4096+wid*512); \
    } }

  f32x4 acc[4][FN];
  #pragma unroll
  for(int m=0;m<4;m++)
    #pragma unroll
    for(int n=0;n<FN;n++) acc[m][n]=(f32x4){0.f,0.f,0.f,0.f};

  STAGEA(0,0);
  __syncthreads();

  const int xr = (lr&7)<<3;
  for(int t=0;t<NT;t++){
    if(t+1<NT) STAGEA(t+1,(t+1)&1);              // issue-early; lands under this tile's compute
    const unsigned short* As=smem+(t&1)*BUFE;
    const unsigned short* Bs=As+BM*BK;
    #pragma unroll
    for(int kk=0;kk<2;kk++){
      short8 a[4], b[FN];
      #pragma unroll
      for(int m=0;m<4;m++)
        a[m]=*(const short8*)(As + (wr*64+m*16+lr)*BK + ((kk*32+lk)^xr));
      #pragma unroll
      for(int n=0;n<FN;n++)
        b[n]=*(const short8*)(Bs + (wc*WNT+n*16+lr)*BK + ((kk*32+lk)^xr));
      __builtin_amdgcn_s_setprio(1);
      #pragma unroll
      for(int m=0;m<4;m++)
        #pragma unroll
        for(int n=0;n<FN;n++)
          acc[m][n]=__builtin_amdgcn_mfma_f32_16x16x32_bf16(a[m],b[n],acc[m][n],0,0,0);
      __builtin_amdgcn_s_setprio(0);
    }
    __syncthreads();                             // full drain: tile t+1 resident after this
  }
  #undef STAGEA

  const int rl=(lane>>4)*4;
  #pragma unroll
  for(int m=0;m<4;m++){
    int gr0 = m0 + wr*64 + m*16 + rl;
    #pragma unroll
    for(int n=0;n<FN;n++){
      int gc = n0 + wc*WNT + n*16 + lr;
      float bv = p.bias ? p.bias[gc] : 0.f;
      #pragma unroll
      for(int r=0;r<4;r++){
        long ro=(long)(gr0+r);
        float val=acc[m][n][r]+bv;
        if(p.relu) val=fmaxf(val,0.f);
        if(p.residF) val += p.residF[ro*(long)p.ldR+gc];
        if(p.residB) val += bf2f(p.residB[ro*(long)p.ldR+gc]);
        long oo = (long)z*p.sO1 + ro*(long)p.ldO+gc;
        if(p.outF) p.outF[oo]=val;
        if(p.outB) p.outB[oo]=f2bf(val);
      }
    }
  }
}

static inline void launch_gemmA(GemmP& p,int M,int N,int Z,hipStream_t s){
  gemmA_k<<<dim3(N/128,M/128,Z),dim3(512),0,s>>>(p);
}

// ---------------- engine B: 256x256, 8 waves (wave tile 128x64), BK=64,
//   2 LDS buffers (128KB), distance-1 issue-early staging, __syncthreads full-drain,
//   both-sides (row&7) swizzle, setprio ----------------
// MODE 0: generic epilogue; MODE 1: QKV split epilogue
template<int MODE>
__global__ void __launch_bounds__(512,1) gemmB_k(GemmP p)
{
  constexpr int BM=256, BN=256, BK=64;
  constexpr int BUFE=(BM+BN)*BK;                 // 32768 elems (64 KB)
  __shared__ __align__(16) unsigned short smem[2*BUFE];   // 128 KB
  const int tid=threadIdx.x, lane=tid&63, wid=tid>>6;
  const int wr=wid>>2, wc=wid&3;                 // 2M x 4N waves, wave tile 128x64
  const int lr=lane&15, lk=(lane>>4)*8;
  const int m0=blockIdx.y*BM, n0=blockIdx.x*BN;
  const unsigned short* Ap=p.A;
  const unsigned short* Bp=p.B;
  const int NT=p.K/BK;

  const int sr8 = lane>>3;
  const int scol = ((lane&7) ^ sr8) << 3;

  #define STAGEB(T,BI) { \
    const long kb_=(long)(T)*BK; \
    unsigned short* As_=smem+(BI)*BUFE; \
    unsigned short* Bs_=As_+BM*BK; \
    _Pragma("unroll") \
    for(int L=0;L<4;L++){ \
      int r_=L*64+wid*8+sr8; \
      gload16(Ap+(long)(m0+r_)*p.ldA+kb_+scol, As_+L*4096+wid*512); \
    } \
    _Pragma("unroll") \
    for(int L=0;L<4;L++){ \
      int r_=L*64+wid*8+sr8; \
      gload16(Bp+(long)(n0+r_)*p.ldB+kb_+scol, Bs_+L*4096+wid*512); \
    } }

  f32x4 acc[8][4];
  #pragma unroll
  for(int m=0;m<8;m++)
    #pragma unroll
    for(int n=0;n<4;n++) acc[m][n]=(f32x4){0.f,0.f,0.f,0.f};

  STAGEB(0,0);
  __syncthreads();

  const int xr = (lr&7)<<3;
  for(int t=0;t<NT;t++){
    if(t+1<NT) STAGEB(t+1,(t+1)&1);              // lands under ~2500cy of MFMA
    const unsigned short* As=smem+(t&1)*BUFE;
    const unsigned short* Bs=As+BM*BK;
    #pragma unroll
    for(int kk=0;kk<2;kk++){
      short8 a[8], b[4];
      #pragma unroll
      for(int m=0;m<8;m++)
        a[m]=*(const short8*)(As + (wr*128+m*16+lr)*BK + ((kk*32+lk)^xr));
      #pragma unroll
      for(int n=0;n<4;n++)
        b[n]=*(const short8*)(Bs + (wc*64+n*16+lr)*BK + ((kk*32+lk)^xr));
      __builtin_amdgcn_s_setprio(1);
      #pragma unroll
      for(int m=0;m<8;m++)
        #pragma unroll
        for(int n=0;n<4;n++)
          acc[m][n]=__builtin_amdgcn_mfma_f32_16x16x32_bf16(a[m],b[n],acc[m][n],0,0,0);
      __builtin_amdgcn_s_setprio(0);
    }
    __syncthreads();
  }
  #undef STAGEB

  const int rl=(lane>>4)*4;
  if(MODE==1){
    int sec = n0>>10;    // 0=Q,1=K,2=V (tiles never straddle 1024 boundaries)
    #pragma unroll
    for(int m=0;m<8;m++){
      int gr0 = m0 + wr*128 + m*16 + rl;
      int b = gr0>>9, s0 = gr0&511;
      #pragma unroll
      for(int n=0;n<4;n++){
        int gc = n0 + wc*64 + n*16 + lr;
        if(sec==0){
          #pragma unroll
          for(int r=0;r<4;r++)
            p.outB[(long)(gr0+r)*1024 + gc] = f2bf(acc[m][n][r]);
        } else {
          unsigned short* dst = sec==1 ? p.kt : p.vt;
          int hh=(gc>>6)&15, d=gc&63;
          ushort4v pk;
          pk.x=f2bf(acc[m][n][0]); pk.y=f2bf(acc[m][n][1]);
          pk.z=f2bf(acc[m][n][2]); pk.w=f2bf(acc[m][n][3]);
          *(ushort4v*)(dst + (((long)b*HH+hh)*DKK+d)*SS + s0) = pk;
        }
      }
    }
  } else {
    #pragma unroll
    for(int m=0;m<8;m++){
      int gr0 = m0 + wr*128 + m*16 + rl;
      #pragma unroll
      for(int n=0;n<4;n++){
        int gc = n0 + wc*64 + n*16 + lr;
        float bv = p.bias ? p.bias[gc] : 0.f;
        #pragma unroll
        for(int r=0;r<4;r++){
          long ro=(long)(gr0+r);
          float val=acc[m][n][r]+bv;
          if(p.relu) val=fmaxf(val,0.f);
          if(p.residF) val += p.residF[ro*(long)p.ldR+gc];
          if(p.residB) val += bf2f(p.residB[ro*(long)p.ldR+gc]);
          long oo = ro*(long)p.ldO+gc;
          if(p.outF) p.outF[oo]=val;
          if(p.outB) p.outB[oo]=f2bf(val);
        }
      }
    }
  }
}

template<int MODE>
static inline void launch_gemmB(GemmP& p,int M,int N,hipStream_t s){
  gemmB_k<MODE><<<dim3(N/256,M/256),dim3(512),0,s>>>(p);
}

// ------- fused attention: S = Q·KRT^T -> mask/scale/softmax -> p fp32 (d_out)
//         then PV in-kernel: att = p @ V -> attb bf16 -------
__global__ void __launch_bounds__(512) att_k(const unsigned short* __restrict__ Qb,
    const unsigned short* __restrict__ KRT, float* __restrict__ pout,
    const unsigned* __restrict__ maskb, const unsigned short* __restrict__ Vt,
    unsigned short* __restrict__ attb)
{
  constexpr int BM=128, BK=32, NT=512;
  constexpr int FM=4, FN=8;                    // QK: 8 waves = 2M x 4N, wave tile 64x128
  __shared__ __align__(16) char smem[49152];
  unsigned short* As = (unsigned short*)smem;            // 8KB  [128*32]
  unsigned short* Bs = (unsigned short*)(smem+8192);     // 32KB [512*32]
  unsigned short* Ps = (unsigned short*)smem;            // 32KB [128*128]  (aliases As/Bs, QK-dead)
  unsigned short* Vs = (unsigned short*)(smem+32768);    // 16KB [64*128]   (aliases Bs tail)
  __shared__ float redmx[BM][4];
  __shared__ float redsm[BM][4];
  int bh = blockIdx.y; int b = bh>>4, h = bh&15;
  const unsigned short* Ap = Qb + (long)b*SS*1024 + h*64;     // Q
  const unsigned short* Bp = KRT + (long)b*SS*1024 + h*64;    // KRT rows (ld 1024)
  int m0 = blockIdx.x*BM;
  int tid=threadIdx.x, lane=tid&63, wid=tid>>6;
  int wr=wid>>2, wc=wid&3;
  f32x4 acc[FM][FN];
  #pragma unroll
  for(int i=0;i<FM;i++)
    #pragma unroll
    for(int j=0;j<FN;j++) acc[i][j]=(f32x4){0.f,0.f,0.f,0.f};
  const int lr=lane&15, lk=(lane>>4)*8;
  for(int k0=0;k0<DKK;k0+=BK){
    { int v=tid;
      gload16(Ap + (long)(m0+(v>>2))*1024 + k0 + (v&3)*8, As + (wid*64)*8); }
    #pragma unroll
    for(int r=0;r<4;r++){
      int v=r*NT+tid;
      gload16(Bp + (long)(v>>2)*1024 + k0 + (v&3)*8, Bs + (r*NT+wid*64)*8);
    }
    __syncthreads();
    short8 af[FM], bfr[FN];
    #pragma unroll
    for(int i=0;i<FM;i++) af[i]=*(const short8*)(As + (wr*64+i*16+lr)*BK + lk);
    #pragma unroll
    for(int j=0;j<FN;j++) bfr[j]=*(const short8*)(Bs + (wc*128+j*16+lr)*BK + lk);
    #pragma unroll
    for(int i=0;i<FM;i++)
      #pragma unroll
      for(int j=0;j<FN;j++)
        acc[i][j]=__builtin_amdgcn_mfma_f32_16x16x32_bf16(af[i],bfr[j],acc[i][j],0,0,0);
    __syncthreads();
  }
  const int rl=(lane>>4)*4;
  // mask (bit-packed) + scale + per-row max
  #pragma unroll
  for(int i=0;i<FM;i++){
    #pragma unroll
    for(int r=0;r<4;r++){
      int row=wr*64+i*16+rl+r;
      uint4 mw = *((const uint4*)(maskb + ((long)(b*SS+m0+row))*16 + wc*4));
      float m_=-3.4e38f;
      #pragma unroll
      for(int j=0;j<FN;j++){
        unsigned word = (j>>1)==0? mw.x : (j>>1)==1? mw.y : (j>>1)==2? mw.z : mw.w;
        float v = ((word>>(((j&1)<<4)+lr))&1) ? NEGV : acc[i][j][r]*0.125f;
        acc[i][j][r]=v; m_=fmaxf(m_,v);
      }
      #pragma unroll
      for(int o=1;o<16;o<<=1) m_=fmaxf(m_,__shfl_xor(m_,o));
      if(lr==0) redmx[row][wc]=m_;
    }
  }
  __syncthreads();
  #pragma unroll
  for(int i=0;i<FM;i++){
    #pragma unroll
    for(int r=0;r<4;r++){
      int row=wr*64+i*16+rl+r;
      float m_=fmaxf(fmaxf(redmx[row][0],redmx[row][1]),fmaxf(redmx[row][2],redmx[row][3]));
      float s_=0.f;
      #pragma unroll
      for(int j=0;j<FN;j++){
        float e=__expf(acc[i][j][r]-m_);
        acc[i][j][r]=e; s_+=e;
      }
      #pragma unroll
      for(int o=1;o<16;o<<=1) s_+=__shfl_xor(s_,o);
      if(lr==0) redsm[row][wc]=s_;
    }
  }
  __syncthreads();
  // normalize + write p fp32 (attns output)
  #pragma unroll
  for(int i=0;i<FM;i++){
    #pragma unroll
    for(int r=0;r<4;r++){
      int row=wr*64+i*16+rl+r;
      float inv=1.f/(redsm[row][0]+redsm[row][1]+redsm[row][2]+redsm[row][3]);
      long obase=((long)bh*SS + m0+row)*(long)SS;
      #pragma unroll
      for(int j=0;j<FN;j++){
        int col=wc*128+j*16+lr;
        float pv=acc[i][j][r]*inv;
        acc[i][j][r]=pv;
        pout[obase+col]=pv;
      }
    }
  }
  __syncthreads();   // QK-phase LDS fully dead before Ps/Vs staging
  // ---- PV: att[128,64] = p[128,512] @ V[512,64], K-chunks of 128 ----
  f32x4 attacc[4];
  #pragma unroll
  for(int j=0;j<4;j++) attacc[j]=(f32x4){0.f,0.f,0.f,0.f};
  for(int kc=0;kc<4;kc++){
    // stage V chunk [64 d][128 k] from Vt, source pre-swizzled (read-XOR = (d&7)<<3 elems)
    #pragma unroll
    for(int r2=0;r2<2;r2++){
      int v=r2*512+tid;
      int d=v>>4, m=v&15;
      int u=m^(d&7);
      gload16(Vt + ((long)bh*64 + d)*512 + kc*128 + u*8, Vs + (r2*512 + wid*64)*8);
    }
    // stage P chunk from acc (only waves owning this 128-col chunk)
    if(wc==kc){
      #pragma unroll
      for(int i=0;i<FM;i++){
        #pragma unroll
        for(int r=0;r<4;r++){
          int row=wr*64+i*16+rl+r;
          #pragma unroll
          for(int j=0;j<FN;j++){
            int col=j*16+lr;
            Ps[row*128 + (col ^ ((row&7)<<3))] = f2bf(acc[i][j][r]);
          }
        }
      }
    }
    __syncthreads();
    #pragma unroll
    for(int kk=0;kk<4;kk++){
      int arow=wid*16+lr;
      short8 paf=*(const short8*)(Ps + arow*128 + ((kk*32+lk) ^ ((arow&7)<<3)));
      #pragma unroll
      for(int j=0;j<4;j++){
        int d=j*16+lr;
        short8 vbf=*(const short8*)(Vs + d*128 + ((kk*32+lk) ^ ((d&7)<<3)));
        attacc[j]=__builtin_amdgcn_mfma_f32_16x16x32_bf16(paf,vbf,attacc[j],0,0,0);
      }
    }
    __syncthreads();
  }
  // epilogue: attb[(b*S + row)][h*64 + d]
  #pragma unroll
  for(int j=0;j<4;j++){
    #pragma unroll
    for(int r=0;r<4;r++){
      int row = m0 + wid*16 + rl + r;
      attb[((long)b*SS + row)*DD + h*64 + j*16 + lr] = f2bf(attacc[j][r]);
    }
  }
}

extern "C" void kernel_launch(void* const* d_in, const int* in_sizes, int n_in,
                              void* d_out, int out_size, void* d_ws, size_t ws_size,
                              hipStream_t stream)
{
  const float* x    =(const float*)d_in[0];
  const int*   mask =(const int*)d_in[1];
  const float* rel  =(const float*)d_in[2];
  const float* Wq   =(const float*)d_in[3];
  const float* Wk   =(const float*)d_in[4];
  const float* Wv   =(const float*)d_in[5];
  const float* Wo   =(const float*)d_in[6];
  const float* bo   =(const float*)d_in[7];
  const float* ln_g =(const float*)d_in[8];
  const float* ln_b =(const float*)d_in[9];
  const float* ln2_g=(const float*)d_in[10];
  const float* ln2_b=(const float*)d_in[11];
  const float* W1   =(const float*)d_in[12];
  const float* b1   =(const float*)d_in[13];
  const float* W2   =(const float*)d_in[14];
  const float* b2   =(const float*)d_in[15];
  const float* lnf_g=(const float*)d_in[16];
  const float* lnf_b=(const float*)d_in[17];
  float* out=(float*)d_out;

  char* w=(char*)d_ws;
  auto alloc=[&](long bytes)->void*{ void* p=(void*)w; w += (bytes+255)&~255L; return p; };
  unsigned short* WTqkv=(unsigned short*)alloc((long)LL*3072*1024*2);
  unsigned short* WoT  =(unsigned short*)alloc((long)LL*1024*1024*2);
  unsigned short* W1T  =(unsigned short*)alloc((long)LL*DFF_*DD*2);
  unsigned short* W2T  =(unsigned short*)alloc((long)LL*DD*DFF_*2);
  unsigned short* relT =(unsigned short*)alloc((long)BB*SS*SS*2);
  unsigned short* qin_b=(unsigned short*)alloc((long)BS*DD*2);
  unsigned short* Qb   =(unsigned short*)alloc((long)BS*1024*2);
  unsigned short* Vt   =(unsigned short*)alloc((long)BB*HH*DKK*SS*2);
  unsigned short* Kt   =(unsigned short*)alloc((long)BB*HH*DKK*SS*2);
  unsigned short* KRT  =(unsigned short*)alloc((long)BB*SS*1024*2);
  unsigned short* attb =(unsigned short*)alloc((long)BS*DD*2);
  float*          attres=(float*)alloc((long)BS*DD*4);
  unsigned short* gbuf =(unsigned short*)alloc((long)BS*DFF_*2);
  float*          hbuf =(float*)alloc((long)BS*DD*4);
  unsigned*       maskb=(unsigned*)alloc((long)BS*16*4);
  (void)ws_size; (void)in_sizes; (void)n_in; (void)out_size;

  // single setup launch: all weight transposes + relation transpose
  TrPack tp;
  auto set=[&](int i, const float* in, unsigned short* o, int ldin, int ldout,
               long is1, long os1, int zd, long is2, long os2, int gx, int gy){
    tp.d[i]={in,o,is1,is2,os1,os2,ldin,ldout,zd,gx,gy};
  };
  set(0, Wq, WTqkv,           1024,1024,(long)1024*1024,(long)3072*1024,1,0,0, 32,32);
  set(1, Wk, WTqkv+1024*1024, 1024,1024,(long)1024*1024,(long)3072*1024,1,0,0, 32,32);
  set(2, Wv, WTqkv+2048*1024, 1024,1024,(long)1024*1024,(long)3072*1024,1,0,0, 32,32);
  set(3, Wo, WoT,             1024,1024,(long)1024*1024,(long)1024*1024,1,0,0, 32,32);
  set(4, W1, W1T, 4096,1024,(long)1024*4096,(long)1024*4096,1,0,0, 128,32);
  set(5, W2, W2T, 1024,4096,(long)4096*1024,(long)4096*1024,1,0,0, 32,128);
  set(6, rel, relT, 512,512,(long)512*512,(long)512*512,1,0,0, 16,16);
  int nb[7]={32*32*LL,32*32*LL,32*32*LL,32*32*LL,128*32*LL,32*128*LL,16*16*BB};
  tp.cum[0]=0;
  for(int i=0;i<7;i++) tp.cum[i+1]=tp.cum[i]+nb[i];
  tr_multi_k<<<dim3(tp.cum[7]),dim3(32,8),0,stream>>>(tp);
  maskpack_k<<<dim3(BS*16/256),dim3(256),0,stream>>>(mask, maskb);

  const float* hin = x;
  for(int l=0;l<LL;l++){
    // q_in = LN(h) -> bf16
    ln_k<<<dim3(BS),dim3(256),0,stream>>>(hin, ln_g+l*DD, ln_b+l*DD, (float*)nullptr, qin_b, (const float*)nullptr);
    // QKV = q_in @ [Wq|Wk|Wv]  (engine B, 256^2); epilogue: Qb + Kt/Vt transposed
    { GemmP p{}; p.A=qin_b; p.ldA=DD; p.B=WTqkv+(long)l*3072*1024; p.ldB=DD;
      p.outB=Qb; p.kt=Kt; p.vt=Vt; p.K=DD;
      launch_gemmB<1>(p, BS, 3072, stream); }
    // KRT[b][n][h*64+d] = sum_k rel[k,n] K[k,hd]  (8 batched GEMMs, engine A)
    { GemmP p{}; p.A=relT; p.sA1=(long)SS*SS; p.ldA=SS;
      p.B=Kt; p.sB1=(long)HH*DKK*SS; p.ldB=SS;
      p.outB=KRT; p.sO1=(long)SS*1024; p.ldO=1024; p.K=SS;
      launch_gemmA(p, SS, 1024, BB, stream); }
    // fused scores+softmax+PV
    float* attn_l = out + (long)BS*DD + (long)l*BB*HH*SS*SS;
    att_k<<<dim3(SS/128, BB*HH),dim3(512),0,stream>>>(Qb, KRT, attn_l, maskb, Vt, attb);
    // attres = att @ Wo + bo + q_in(bf16)  (engine A)
    { GemmP p{}; p.A=attb; p.ldA=DD; p.B=WoT+(long)l*1024*1024; p.ldB=DD;
      p.outF=attres; p.ldO=DD; p.bias=bo+l*DD;
      p.residB=qin_b; p.ldR=DD; p.K=DD;
      launch_gemmA(p, BS, DD, 1, stream); }
    // h = hin + LN2(attres) -> hbuf ; f = LN1(h) -> qin_b
    ln2_k<<<dim3(BS),dim3(256),0,stream>>>(attres, hin, ln2_g+l*DD, ln2_b+l*DD,
        ln_g+l*DD, ln_b+l*DD, hbuf, qin_b);
    // g = relu(f @ W1 + b1)  (engine B, 256^2)
    { GemmP p{}; p.A=qin_b; p.ldA=DD; p.B=W1T+(long)l*DFF_*DD; p.ldB=DD;
      p.outB=gbuf; p.ldO=DFF_; p.bias=b1+l*DFF_; p.relu=1; p.K=DD;
      launch_gemmB<0>(p, BS, DFF_, stream); }
    // h += g @ W2 + b2  (engine A)
    { GemmP p{}; p.A=gbuf; p.ldA=DFF_; p.B=W2T+(long)l*DD*DFF_; p.ldB=DFF_;
      p.outF=hbuf; p.ldO=DD; p.bias=b2+l*DD;
      p.residF=hbuf; p.ldR=DD; p.K=DFF_;
      launch_gemmA(p, BS, DD, 1, stream); }
    hin=hbuf;
  }
  ln_k<<<dim3(BS),dim3(256),0,stream>>>(hbuf, lnf_g, lnf_b, out, (unsigned short*)nullptr, (const float*)nullptr);
}

// Round 13
// 1980.932 us; speedup vs baseline: 1.0421x; 1.0421x over previous
//
#include <hip/hip_runtime.h>
#include <hip/hip_bf16.h>
#include <stdint.h>

#define LL 6
#define DD 1024
#define HH 16
#define DKK 64
#define SS 512
#define BB 8
#define DFF_ 4096
#define BS (BB*SS)
#define NEGV -1.0e9f

typedef __attribute__((ext_vector_type(8))) short short8;
typedef __attribute__((ext_vector_type(4))) float f32x4;
typedef __attribute__((ext_vector_type(4))) unsigned short ushort4v;

static __device__ __forceinline__ float bf2f(unsigned short u){
  union { unsigned int i; float f; } v; v.i = ((unsigned int)u)<<16; return v.f;
}
static __device__ __forceinline__ unsigned short f2bf(float f){
  union { float f; unsigned int i; } v; v.f=f;
  unsigned int r = v.i + 0x7fff + ((v.i>>16)&1);   // RNE
  return (unsigned short)(r>>16);
}

static __device__ __forceinline__ void gload16(const void* g, void* l){
  __builtin_amdgcn_global_load_lds((const __attribute__((address_space(1))) unsigned int*)g,
                                   (__attribute__((address_space(3))) unsigned int*)l, 16, 0, 0);
}

// ---------------- multi-descriptor fp32->bf16 transpose: out[c][r] = in[r][c] ----------------
struct TrDesc { const float* in; unsigned short* out; long is1,is2,os1,os2; int ldin,ldout,zd,gx,gy; };
struct TrPack { TrDesc d[7]; int cum[8]; };

__global__ void __launch_bounds__(256) tr_multi_k(TrPack P)
{
  __shared__ float t[32][33];
  int bid=blockIdx.x, di=0;
  #pragma unroll
  for(int k=1;k<7;k++) if(bid>=P.cum[k]) di=k;
  TrDesc dd=P.d[di];
  int local=bid-P.cum[di];
  int bx=local%dd.gx; int rest=local/dd.gx;
  int by=rest%dd.gy; int z=rest/dd.gy;
  int z1=z/dd.zd, z2=z%dd.zd;
  const float* ip=dd.in+z1*dd.is1+z2*dd.is2;
  unsigned short* op=dd.out+z1*dd.os1+z2*dd.os2;
  int r0=by*32, c0=bx*32;
  int tx=threadIdx.x, ty=threadIdx.y;
  #pragma unroll
  for(int i=0;i<4;i++)
    t[ty+i*8][tx] = ip[(long)(r0+ty+i*8)*dd.ldin + c0+tx];
  __syncthreads();
  #pragma unroll
  for(int i=0;i<4;i++)
    op[(long)(c0+ty+i*8)*dd.ldout + r0+tx] = f2bf(t[tx][ty+i*8]);
}

// ---------------- mask bit-pack ----------------
__global__ void __launch_bounds__(256) maskpack_k(const int* __restrict__ mask, unsigned* __restrict__ mb)
{
  int idx = blockIdx.x*256 + threadIdx.x;     // idx = row*16 + w
  int row = idx>>4, w = idx&15;
  const int* mp = mask + (long)row*SS + w*32;
  unsigned v=0;
  #pragma unroll
  for(int i=0;i<32;i++) v |= (mp[i]!=0) ? (1u<<i) : 0u;
  mb[idx]=v;
}

// ---------------- LayerNorm: out = LN(src)*g+b (+resid); fp32 and/or bf16 out ----------------
__global__ void __launch_bounds__(256) ln_k(const float* __restrict__ src,
    const float* __restrict__ gw, const float* __restrict__ bw,
    float* __restrict__ outf, unsigned short* __restrict__ outb,
    const float* __restrict__ resid)
{
  long row=blockIdx.x;
  float4 v=((const float4*)(src+row*DD))[threadIdx.x];
  float s=v.x+v.y+v.z+v.w;
  float s2=v.x*v.x+v.y*v.y+v.z*v.z+v.w*v.w;
  #pragma unroll
  for(int o=32;o;o>>=1){ s+=__shfl_xor(s,o); s2+=__shfl_xor(s2,o); }
  __shared__ float red[8];
  int wid=threadIdx.x>>6, lane=threadIdx.x&63;
  if(lane==0){ red[wid]=s; red[4+wid]=s2; }
  __syncthreads();
  s=red[0]+red[1]+red[2]+red[3];
  s2=red[4]+red[5]+red[6]+red[7];
  float mu=s*(1.f/DD);
  float rstd=rsqrtf(s2*(1.f/DD)-mu*mu+1e-5f);
  int c=threadIdx.x*4;
  float4 g4=*(const float4*)(gw+c), b4=*(const float4*)(bw+c);
  float4 o;
  o.x=(v.x-mu)*rstd*g4.x+b4.x;
  o.y=(v.y-mu)*rstd*g4.y+b4.y;
  o.z=(v.z-mu)*rstd*g4.z+b4.z;
  o.w=(v.w-mu)*rstd*g4.w+b4.w;
  if(resid){
    float4 r4=((const float4*)(resid+row*DD))[threadIdx.x];
    o.x+=r4.x; o.y+=r4.y; o.z+=r4.z; o.w+=r4.w;
  }
  if(outf) ((float4*)(outf+row*DD))[threadIdx.x]=o;
  if(outb){
    uint2 pk;
    pk.x=(unsigned)f2bf(o.x)|((unsigned)f2bf(o.y)<<16);
    pk.y=(unsigned)f2bf(o.z)|((unsigned)f2bf(o.w)<<16);
    ((uint2*)(outb+row*DD))[threadIdx.x]=pk;
  }
}

// ---------------- fused: t = LN(src;g2,b2)+resid -> outf;  LN(t;g1,b1) -> outb ----------------
__global__ void __launch_bounds__(256) ln2_k(const float* __restrict__ src,
    const float* __restrict__ resid,
    const float* __restrict__ g2, const float* __restrict__ b2,
    const float* __restrict__ g1, const float* __restrict__ b1,
    float* __restrict__ outf, unsigned short* __restrict__ outb)
{
  long row=blockIdx.x;
  int wid=threadIdx.x>>6, lane=threadIdx.x&63, c=threadIdx.x*4;
  __shared__ float red[8];
  float4 v=((const float4*)(src+row*DD))[threadIdx.x];
  float s=v.x+v.y+v.z+v.w;
  float s2=v.x*v.x+v.y*v.y+v.z*v.z+v.w*v.w;
  #pragma unroll
  for(int o=32;o;o>>=1){ s+=__shfl_xor(s,o); s2+=__shfl_xor(s2,o); }
  if(lane==0){ red[wid]=s; red[4+wid]=s2; }
  __syncthreads();
  s=red[0]+red[1]+red[2]+red[3];
  s2=red[4]+red[5]+red[6]+red[7];
  float mu=s*(1.f/DD);
  float rstd=rsqrtf(s2*(1.f/DD)-mu*mu+1e-5f);
  float4 g4=*(const float4*)(g2+c), b4=*(const float4*)(b2+c);
  float4 r4=((const float4*)(resid+row*DD))[threadIdx.x];
  float4 o;
  o.x=(v.x-mu)*rstd*g4.x+b4.x+r4.x;
  o.y=(v.y-mu)*rstd*g4.y+b4.y+r4.y;
  o.z=(v.z-mu)*rstd*g4.z+b4.z+r4.z;
  o.w=(v.w-mu)*rstd*g4.w+b4.w+r4.w;
  ((float4*)(outf+row*DD))[threadIdx.x]=o;
  s=o.x+o.y+o.z+o.w;
  s2=o.x*o.x+o.y*o.y+o.z*o.z+o.w*o.w;
  #pragma unroll
  for(int of=32;of;of>>=1){ s+=__shfl_xor(s,of); s2+=__shfl_xor(s2,of); }
  __syncthreads();
  if(lane==0){ red[wid]=s; red[4+wid]=s2; }
  __syncthreads();
  s=red[0]+red[1]+red[2]+red[3];
  s2=red[4]+red[5]+red[6]+red[7];
  mu=s*(1.f/DD);
  rstd=rsqrtf(s2*(1.f/DD)-mu*mu+1e-5f);
  g4=*(const float4*)(g1+c); b4=*(const float4*)(b1+c);
  uint2 pk;
  pk.x=(unsigned)f2bf((o.x-mu)*rstd*g4.x+b4.x)|((unsigned)f2bf((o.y-mu)*rstd*g4.y+b4.y)<<16);
  pk.y=(unsigned)f2bf((o.z-mu)*rstd*g4.z+b4.z)|((unsigned)f2bf((o.w-mu)*rstd*g4.w+b4.w)<<16);
  ((uint2*)(outb+row*DD))[threadIdx.x]=pk;
}

// ---------------- GEMM params ----------------
struct GemmP {
  const unsigned short* A; long sA1; int ldA;
  const unsigned short* B; long sB1; int ldB;
  float* outF; unsigned short* outB; long sO1; int ldO;
  const float* bias;
  const float* residF; int ldR;
  const unsigned short* residB;
  unsigned short *kt, *vt;
  int K, relu, mb;
};

// XCD-bijective m-major block remap (requires gridDim.x % 8 == 0):
// consecutive nb share n0 (B-panel); each XCD gets a contiguous nb chunk.
static __device__ __forceinline__ void xcd_map(int mb,int BM,int BN,int& m0,int& n0){
  const int nwg=gridDim.x, bid=blockIdx.x;
  const int nb=(bid&7)*(nwg>>3)+(bid>>3);
  m0=(nb%mb)*BM; n0=(nb/mb)*BN;
}

// ---------------- engine A (R10-proven): 128x128, 8 waves (wt 64x32), BK=64, 4 LDS buffers,
//   pair-unroll (2 K-tiles per barrier), __syncthreads full-drain, both-sides swizzle ----------------
__global__ void __launch_bounds__(512,2) gemmA_k(GemmP p)
{
  constexpr int BM=128, BN=128, BK=64;
  constexpr int BUFE=(BM+BN)*BK;
  constexpr int FN=2;
  constexpr int WNT=32;
  __shared__ __align__(16) unsigned short smem[4*BUFE];   // 128 KB
  const int tid=threadIdx.x, lane=tid&63, wid=tid>>6;
  const int wr=wid>>2, wc=wid&3;
  const int lr=lane&15, lk=(lane>>4)*8;
  int m0,n0; xcd_map(p.mb,BM,BN,m0,n0);
  const int z=blockIdx.y;
  const unsigned short* Ap=p.A+(long)z*p.sA1;
  const unsigned short* Bp=p.B+(long)z*p.sB1;
  const int NT=p.K/BK;

  const int sr8 = lane>>3;
  const int scol = ((lane&7) ^ sr8) << 3;

  #define STAGEA(T,BI) { \
    const long kb_=(long)(T)*BK; \
    unsigned short* As_=smem+(BI)*BUFE; \
    unsigned short* Bs_=As_+BM*BK; \
    _Pragma("unroll") \
    for(int L=0;L<2;L++){ \
      int r_=L*64+wid*8+sr8; \
      gload16(Ap+(long)(m0+r_)*p.ldA+kb_+scol, As_+L*4096+wid*512); \
    } \
    _Pragma("unroll") \
    for(int L=0;L<2;L++){ \
      int r_=L*64+wid*8+sr8; \
      gload16(Bp+(long)(n0+r_)*p.ldB+kb_+scol, Bs_+L*4096+wid*512); \
    } }

  f32x4 acc[4][FN];
  #pragma unroll
  for(int m=0;m<4;m++)
    #pragma unroll
    for(int n=0;n<FN;n++) acc[m][n]=(f32x4){0.f,0.f,0.f,0.f};

  STAGEA(0,0);
  STAGEA(1,1);
  __syncthreads();

  const int xr = (lr&7)<<3;
  for(int t=0;t<NT;t+=2){
    if(t+2<NT) STAGEA(t+2,(t+2)&3);
    if(t+3<NT) STAGEA(t+3,(t+3)&3);
    #pragma unroll
    for(int u=0;u<2;u++){
      const unsigned short* As=smem+((t+u)&3)*BUFE;
      const unsigned short* Bs=As+BM*BK;
      #pragma unroll
      for(int kk=0;kk<2;kk++){
        short8 a[4], b[FN];
        #pragma unroll
        for(int m=0;m<4;m++)
          a[m]=*(const short8*)(As + (wr*64+m*16+lr)*BK + ((kk*32+lk)^xr));
        #pragma unroll
        for(int n=0;n<FN;n++)
          b[n]=*(const short8*)(Bs + (wc*WNT+n*16+lr)*BK + ((kk*32+lk)^xr));
        __builtin_amdgcn_s_setprio(1);
        #pragma unroll
        for(int m=0;m<4;m++)
          #pragma unroll
          for(int n=0;n<FN;n++)
            acc[m][n]=__builtin_amdgcn_mfma_f32_16x16x32_bf16(a[m],b[n],acc[m][n],0,0,0);
        __builtin_amdgcn_s_setprio(0);
      }
    }
    __syncthreads();
  }
  #undef STAGEA

  const int rl=(lane>>4)*4;
  #pragma unroll
  for(int m=0;m<4;m++){
    int gr0 = m0 + wr*64 + m*16 + rl;
    #pragma unroll
    for(int n=0;n<FN;n++){
      int gc = n0 + wc*WNT + n*16 + lr;
      float bv = p.bias ? p.bias[gc] : 0.f;
      #pragma unroll
      for(int r=0;r<4;r++){
        long ro=(long)(gr0+r);
        float val=acc[m][n][r]+bv;
        if(p.relu) val=fmaxf(val,0.f);
        if(p.residF) val += p.residF[ro*(long)p.ldR+gc];
        if(p.residB) val += bf2f(p.residB[ro*(long)p.ldR+gc]);
        long oo = (long)z*p.sO1 + ro*(long)p.ldO+gc;
        if(p.outF) p.outF[oo]=val;
        if(p.outB) p.outB[oo]=f2bf(val);
      }
    }
  }
}

static inline void launch_gemmA(GemmP& p,int M,int N,int Z,hipStream_t s){
  p.mb=M/128;
  gemmA_k<<<dim3((M/128)*(N/128),Z),dim3(512),0,s>>>(p);
}

// ---------------- engine B: 256x256, 8 waves (wave tile 128x64), BK=64,
//   2 LDS buffers (128KB), distance-1 issue-early staging, __syncthreads full-drain,
//   both-sides (row&7) swizzle, setprio ----------------
// MODE 0: generic epilogue; MODE 1: QKV split epilogue
template<int MODE>
__global__ void __launch_bounds__(512,1) gemmB_k(GemmP p)
{
  constexpr int BM=256, BN=256, BK=64;
  constexpr int BUFE=(BM+BN)*BK;                 // 32768 elems (64 KB)
  __shared__ __align__(16) unsigned short smem[2*BUFE];   // 128 KB
  const int tid=threadIdx.x, lane=tid&63, wid=tid>>6;
  const int wr=wid>>2, wc=wid&3;                 // 2M x 4N waves, wave tile 128x64
  const int lr=lane&15, lk=(lane>>4)*8;
  int m0,n0; xcd_map(p.mb,BM,BN,m0,n0);
  const unsigned short* Ap=p.A;
  const unsigned short* Bp=p.B;
  const int NT=p.K/BK;

  const int sr8 = lane>>3;
  const int scol = ((lane&7) ^ sr8) << 3;

  #define STAGEB(T,BI) { \
    const long kb_=(long)(T)*BK; \
    unsigned short* As_=smem+(BI)*BUFE; \
    unsigned short* Bs_=As_+BM*BK; \
    _Pragma("unroll") \
    for(int L=0;L<4;L++){ \
      int r_=L*64+wid*8+sr8; \
      gload16(Ap+(long)(m0+r_)*p.ldA+kb_+scol, As_+L*4096+wid*512); \
    } \
    _Pragma("unroll") \
    for(int L=0;L<4;L++){ \
      int r_=L*64+wid*8+sr8; \
      gload16(Bp+(long)(n0+r_)*p.ldB+kb_+scol, Bs_+L*4096+wid*512); \
    } }

  f32x4 acc[8][4];
  #pragma unroll
  for(int m=0;m<8;m++)
    #pragma unroll
    for(int n=0;n<4;n++) acc[m][n]=(f32x4){0.f,0.f,0.f,0.f};

  STAGEB(0,0);
  __syncthreads();

  const int xr = (lr&7)<<3;
  for(int t=0;t<NT;t++){
    if(t+1<NT) STAGEB(t+1,(t+1)&1);              // lands under ~2500cy of MFMA
    const unsigned short* As=smem+(t&1)*BUFE;
    const unsigned short* Bs=As+BM*BK;
    #pragma unroll
    for(int kk=0;kk<2;kk++){
      short8 a[8], b[4];
      #pragma unroll
      for(int m=0;m<8;m++)
        a[m]=*(const short8*)(As + (wr*128+m*16+lr)*BK + ((kk*32+lk)^xr));
      #pragma unroll
      for(int n=0;n<4;n++)
        b[n]=*(const short8*)(Bs + (wc*64+n*16+lr)*BK + ((kk*32+lk)^xr));
      __builtin_amdgcn_s_setprio(1);
      #pragma unroll
      for(int m=0;m<8;m++)
        #pragma unroll
        for(int n=0;n<4;n++)
          acc[m][n]=__builtin_amdgcn_mfma_f32_16x16x32_bf16(a[m],b[n],acc[m][n],0,0,0);
      __builtin_amdgcn_s_setprio(0);
    }
    __syncthreads();
  }
  #undef STAGEB

  const int rl=(lane>>4)*4;
  if(MODE==1){
    int sec = n0>>10;    // 0=Q,1=K,2=V (tiles never straddle 1024 boundaries)
    #pragma unroll
    for(int m=0;m<8;m++){
      int gr0 = m0 + wr*128 + m*16 + rl;
      int b = gr0>>9, s0 = gr0&511;
      #pragma unroll
      for(int n=0;n<4;n++){
        int gc = n0 + wc*64 + n*16 + lr;
        if(sec==0){
          #pragma unroll
          for(int r=0;r<4;r++)
            p.outB[(long)(gr0+r)*1024 + gc] = f2bf(acc[m][n][r]);
        } else {
          unsigned short* dst = sec==1 ? p.kt : p.vt;
          int hh=(gc>>6)&15, d=gc&63;
          ushort4v pk;
          pk.x=f2bf(acc[m][n][0]); pk.y=f2bf(acc[m][n][1]);
          pk.z=f2bf(acc[m][n][2]); pk.w=f2bf(acc[m][n][3]);
          *(ushort4v*)(dst + (((long)b*HH+hh)*DKK+d)*SS + s0) = pk;
        }
      }
    }
  } else {
    #pragma unroll
    for(int m=0;m<8;m++){
      int gr0 = m0 + wr*128 + m*16 + rl;
      #pragma unroll
      for(int n=0;n<4;n++){
        int gc = n0 + wc*64 + n*16 + lr;
        float bv = p.bias ? p.bias[gc] : 0.f;
        #pragma unroll
        for(int r=0;r<4;r++){
          long ro=(long)(gr0+r);
          float val=acc[m][n][r]+bv;
          if(p.relu) val=fmaxf(val,0.f);
          if(p.residF) val += p.residF[ro*(long)p.ldR+gc];
          if(p.residB) val += bf2f(p.residB[ro*(long)p.ldR+gc]);
          long oo = ro*(long)p.ldO+gc;
          if(p.outF) p.outF[oo]=val;
          if(p.outB) p.outB[oo]=f2bf(val);
        }
      }
    }
  }
}

template<int MODE>
static inline void launch_gemmB(GemmP& p,int M,int N,hipStream_t s){
  p.mb=M/256;
  gemmB_k<MODE><<<dim3((M/256)*(N/256)),dim3(512),0,s>>>(p);
}

// ------- fused attention: S = Q·KRT^T -> mask/scale/softmax -> p fp32 (d_out)
//         then PV in-kernel: att = p @ V -> attb bf16 -------
__global__ void __launch_bounds__(512) att_k(const unsigned short* __restrict__ Qb,
    const unsigned short* __restrict__ KRT, float* __restrict__ pout,
    const unsigned* __restrict__ maskb, const unsigned short* __restrict__ Vt,
    unsigned short* __restrict__ attb)
{
  constexpr int BM=128, BK=32, NT=512;
  constexpr int FM=4, FN=8;                    // QK: 8 waves = 2M x 4N, wave tile 64x128
  __shared__ __align__(16) char smem[49152];
  unsigned short* As = (unsigned short*)smem;            // 8KB  [128*32]
  unsigned short* Bs = (unsigned short*)(smem+8192);     // 32KB [512*32]
  unsigned short* Ps = (unsigned short*)smem;            // 32KB [128*128]  (aliases As/Bs, QK-dead)
  unsigned short* Vs = (unsigned short*)(smem+32768);    // 16KB [64*128]   (aliases Bs tail)
  __shared__ float redmx[BM][4];
  __shared__ float redsm[BM][4];
  int bh = blockIdx.y; int b = bh>>4, h = bh&15;
  const unsigned short* Ap = Qb + (long)b*SS*1024 + h*64;     // Q
  const unsigned short* Bp = KRT + (long)b*SS*1024 + h*64;    // KRT rows (ld 1024)
  int m0 = blockIdx.x*BM;
  int tid=threadIdx.x, lane=tid&63, wid=tid>>6;
  int wr=wid>>2, wc=wid&3;
  f32x4 acc[FM][FN];
  #pragma unroll
  for(int i=0;i<FM;i++)
    #pragma unroll
    for(int j=0;j<FN;j++) acc[i][j]=(f32x4){0.f,0.f,0.f,0.f};
  const int lr=lane&15, lk=(lane>>4)*8;
  for(int k0=0;k0<DKK;k0+=BK){
    { int v=tid;
      gload16(Ap + (long)(m0+(v>>2))*1024 + k0 + (v&3)*8, As + (wid*64)*8); }
    #pragma unroll
    for(int r=0;r<4;r++){
      int v=r*NT+tid;
      gload16(Bp + (long)(v>>2)*1024 + k0 + (v&3)*8, Bs + (r*NT+wid*64)*8);
    }
    __syncthreads();
    short8 af[FM], bfr[FN];
    #pragma unroll
    for(int i=0;i<FM;i++) af[i]=*(const short8*)(As + (wr*64+i*16+lr)*BK + lk);
    #pragma unroll
    for(int j=0;j<FN;j++) bfr[j]=*(const short8*)(Bs + (wc*128+j*16+lr)*BK + lk);
    #pragma unroll
    for(int i=0;i<FM;i++)
      #pragma unroll
      for(int j=0;j<FN;j++)
        acc[i][j]=__builtin_amdgcn_mfma_f32_16x16x32_bf16(af[i],bfr[j],acc[i][j],0,0,0);
    __syncthreads();
  }
  const int rl=(lane>>4)*4;
  // mask (bit-packed) + scale + per-row max
  #pragma unroll
  for(int i=0;i<FM;i++){
    #pragma unroll
    for(int r=0;r<4;r++){
      int row=wr*64+i*16+rl+r;
      uint4 mw = *((const uint4*)(maskb + ((long)(b*SS+m0+row))*16 + wc*4));
      float m_=-3.4e38f;
      #pragma unroll
      for(int j=0;j<FN;j++){
        unsigned word = (j>>1)==0? mw.x : (j>>1)==1? mw.y : (j>>1)==2? mw.z : mw.w;
        float v = ((word>>(((j&1)<<4)+lr))&1) ? NEGV : acc[i][j][r]*0.125f;
        acc[i][j][r]=v; m_=fmaxf(m_,v);
      }
      #pragma unroll
      for(int o=1;o<16;o<<=1) m_=fmaxf(m_,__shfl_xor(m_,o));
      if(lr==0) redmx[row][wc]=m_;
    }
  }
  __syncthreads();
  #pragma unroll
  for(int i=0;i<FM;i++){
    #pragma unroll
    for(int r=0;r<4;r++){
      int row=wr*64+i*16+rl+r;
      float m_=fmaxf(fmaxf(redmx[row][0],redmx[row][1]),fmaxf(redmx[row][2],redmx[row][3]));
      float s_=0.f;
      #pragma unroll
      for(int j=0;j<FN;j++){
        float e=__expf(acc[i][j][r]-m_);
        acc[i][j][r]=e; s_+=e;
      }
      #pragma unroll
      for(int o=1;o<16;o<<=1) s_+=__shfl_xor(s_,o);
      if(lr==0) redsm[row][wc]=s_;
    }
  }
  __syncthreads();
  // normalize + write p fp32 (attns output)
  #pragma unroll
  for(int i=0;i<FM;i++){
    #pragma unroll
    for(int r=0;r<4;r++){
      int row=wr*64+i*16+rl+r;
      float inv=1.f/(redsm[row][0]+redsm[row][1]+redsm[row][2]+redsm[row][3]);
      long obase=((long)bh*SS + m0+row)*(long)SS;
      #pragma unroll
      for(int j=0;j<FN;j++){
        int col=wc*128+j*16+lr;
        float pv=acc[i][j][r]*inv;
        acc[i][j][r]=pv;
        pout[obase+col]=pv;
      }
    }
  }
  __syncthreads();   // QK-phase LDS fully dead before Ps/Vs staging
  // ---- PV: att[128,64] = p[128,512] @ V[512,64], K-chunks of 128 ----
  f32x4 attacc[4];
  #pragma unroll
  for(int j=0;j<4;j++) attacc[j]=(f32x4){0.f,0.f,0.f,0.f};
  for(int kc=0;kc<4;kc++){
    // stage V chunk [64 d][128 k] from Vt, source pre-swizzled (read-XOR = (d&7)<<3 elems)
    #pragma unroll
    for(int r2=0;r2<2;r2++){
      int v=r2*512+tid;
      int d=v>>4, m=v&15;
      int u=m^(d&7);
      gload16(Vt + ((long)bh*64 + d)*512 + kc*128 + u*8, Vs + (r2*512 + wid*64)*8);
    }
    // stage P chunk from acc (only waves owning this 128-col chunk)
    if(wc==kc){
      #pragma unroll
      for(int i=0;i<FM;i++){
        #pragma unroll
        for(int r=0;r<4;r++){
          int row=wr*64+i*16+rl+r;
          #pragma unroll
          for(int j=0;j<FN;j++){
            int col=j*16+lr;
            Ps[row*128 + (col ^ ((row&7)<<3))] = f2bf(acc[i][j][r]);
          }
        }
      }
    }
    __syncthreads();
    #pragma unroll
    for(int kk=0;kk<4;kk++){
      int arow=wid*16+lr;
      short8 paf=*(const short8*)(Ps + arow*128 + ((kk*32+lk) ^ ((arow&7)<<3)));
      #pragma unroll
      for(int j=0;j<4;j++){
        int d=j*16+lr;
        short8 vbf=*(const short8*)(Vs + d*128 + ((kk*32+lk) ^ ((d&7)<<3)));
        attacc[j]=__builtin_amdgcn_mfma_f32_16x16x32_bf16(paf,vbf,attacc[j],0,0,0);
      }
    }
    __syncthreads();
  }
  // epilogue: attb[(b*S + row)][h*64 + d]
  #pragma unroll
  for(int j=0;j<4;j++){
    #pragma unroll
    for(int r=0;r<4;r++){
      int row = m0 + wid*16 + rl + r;
      attb[((long)b*SS + row)*DD + h*64 + j*16 + lr] = f2bf(attacc[j][r]);
    }
  }
}

extern "C" void kernel_launch(void* const* d_in, const int* in_sizes, int n_in,
                              void* d_out, int out_size, void* d_ws, size_t ws_size,
                              hipStream_t stream)
{
  const float* x    =(const float*)d_in[0];
  const int*   mask =(const int*)d_in[1];
  const float* rel  =(const float*)d_in[2];
  const float* Wq   =(const float*)d_in[3];
  const float* Wk   =(const float*)d_in[4];
  const float* Wv   =(const float*)d_in[5];
  const float* Wo   =(const float*)d_in[6];
  const float* bo   =(const float*)d_in[7];
  const float* ln_g =(const float*)d_in[8];
  const float* ln_b =(const float*)d_in[9];
  const float* ln2_g=(const float*)d_in[10];
  const float* ln2_b=(const float*)d_in[11];
  const float* W1   =(const float*)d_in[12];
  const float* b1   =(const float*)d_in[13];
  const float* W2   =(const float*)d_in[14];
  const float* b2   =(const float*)d_in[15];
  const float* lnf_g=(const float*)d_in[16];
  const float* lnf_b=(const float*)d_in[17];
  float* out=(float*)d_out;

  char* w=(char*)d_ws;
  auto alloc=[&](long bytes)->void*{ void* p=(void*)w; w += (bytes+255)&~255L; return p; };
  unsigned short* WTqkv=(unsigned short*)alloc((long)LL*3072*1024*2);
  unsigned short* WoT  =(unsigned short*)alloc((long)LL*1024*1024*2);
  unsigned short* W1T  =(unsigned short*)alloc((long)LL*DFF_*DD*2);
  unsigned short* W2T  =(unsigned short*)alloc((long)LL*DD*DFF_*2);
  unsigned short* relT =(unsigned short*)alloc((long)BB*SS*SS*2);
  unsigned short* qin_b=(unsigned short*)alloc((long)BS*DD*2);
  unsigned short* Qb   =(unsigned short*)alloc((long)BS*1024*2);
  unsigned short* Vt   =(unsigned short*)alloc((long)BB*HH*DKK*SS*2);
  unsigned short* Kt   =(unsigned short*)alloc((long)BB*HH*DKK*SS*2);
  unsigned short* KRT  =(unsigned short*)alloc((long)BB*SS*1024*2);
  unsigned short* attb =(unsigned short*)alloc((long)BS*DD*2);
  float*          attres=(float*)alloc((long)BS*DD*4);
  unsigned short* gbuf =(unsigned short*)alloc((long)BS*DFF_*2);
  float*          hbuf =(float*)alloc((long)BS*DD*4);
  unsigned*       maskb=(unsigned*)alloc((long)BS*16*4);
  (void)ws_size; (void)in_sizes; (void)n_in; (void)out_size;

  // single setup launch: all weight transposes + relation transpose
  TrPack tp;
  auto set=[&](int i, const float* in, unsigned short* o, int ldin, int ldout,
               long is1, long os1, int zd, long is2, long os2, int gx, int gy){
    tp.d[i]={in,o,is1,is2,os1,os2,ldin,ldout,zd,gx,gy};
  };
  set(0, Wq, WTqkv,           1024,1024,(long)1024*1024,(long)3072*1024,1,0,0, 32,32);
  set(1, Wk, WTqkv+1024*1024, 1024,1024,(long)1024*1024,(long)3072*1024,1,0,0, 32,32);
  set(2, Wv, WTqkv+2048*1024, 1024,1024,(long)1024*1024,(long)3072*1024,1,0,0, 32,32);
  set(3, Wo, WoT,             1024,1024,(long)1024*1024,(long)1024*1024,1,0,0, 32,32);
  set(4, W1, W1T, 4096,1024,(long)1024*4096,(long)1024*4096,1,0,0, 128,32);
  set(5, W2, W2T, 1024,4096,(long)4096*1024,(long)4096*1024,1,0,0, 32,128);
  set(6, rel, relT, 512,512,(long)512*512,(long)512*512,1,0,0, 16,16);
  int nb[7]={32*32*LL,32*32*LL,32*32*LL,32*32*LL,128*32*LL,32*128*LL,16*16*BB};
  tp.cum[0]=0;
  for(int i=0;i<7;i++) tp.cum[i+1]=tp.cum[i]+nb[i];
  tr_multi_k<<<dim3(tp.cum[7]),dim3(32,8),0,stream>>>(tp);
  maskpack_k<<<dim3(BS*16/256),dim3(256),0,stream>>>(mask, maskb);

  const float* hin = x;
  for(int l=0;l<LL;l++){
    // q_in = LN(h) -> bf16
    ln_k<<<dim3(BS),dim3(256),0,stream>>>(hin, ln_g+l*DD, ln_b+l*DD, (float*)nullptr, qin_b, (const float*)nullptr);
    // QKV = q_in @ [Wq|Wk|Wv]  (engine B, 256^2); epilogue: Qb + Kt/Vt transposed
    { GemmP p{}; p.A=qin_b; p.ldA=DD; p.B=WTqkv+(long)l*3072*1024; p.ldB=DD;
      p.outB=Qb; p.kt=Kt; p.vt=Vt; p.K=DD;
      launch_gemmB<1>(p, BS, 3072, stream); }
    // KRT[b][n][h*64+d] = sum_k rel[k,n] K[k,hd]  (8 batched GEMMs, engine A)
    { GemmP p{}; p.A=relT; p.sA1=(long)SS*SS; p.ldA=SS;
      p.B=Kt; p.sB1=(long)HH*DKK*SS; p.ldB=SS;
      p.outB=KRT; p.sO1=(long)SS*1024; p.ldO=1024; p.K=SS;
      launch_gemmA(p, SS, 1024, BB, stream); }
    // fused scores+softmax+PV
    float* attn_l = out + (long)BS*DD + (long)l*BB*HH*SS*SS;
    att_k<<<dim3(SS/128, BB*HH),dim3(512),0,stream>>>(Qb, KRT, attn_l, maskb, Vt, attb);
    // attres = att @ Wo + bo + q_in(bf16)  (engine A)
    { GemmP p{}; p.A=attb; p.ldA=DD; p.B=WoT+(long)l*1024*1024; p.ldB=DD;
      p.outF=attres; p.ldO=DD; p.bias=bo+l*DD;
      p.residB=qin_b; p.ldR=DD; p.K=DD;
      launch_gemmA(p, BS, DD, 1, stream); }
    // h = hin + LN2(attres) -> hbuf ; f = LN1(h) -> qin_b
    ln2_k<<<dim3(BS),dim3(256),0,stream>>>(attres, hin, ln2_g+l*DD, ln2_b+l*DD,
        ln_g+l*DD, ln_b+l*DD, hbuf, qin_b);
    // g = relu(f @ W1 + b1)  (engine B, 256^2)
    { GemmP p{}; p.A=qin_b; p.ldA=DD; p.B=W1T+(long)l*DFF_*DD; p.ldB=DD;
      p.outB=gbuf; p.ldO=DFF_; p.bias=b1+l*DFF_; p.relu=1; p.K=DD;
      launch_gemmB<0>(p, BS, DFF_, stream); }
    // h += g @ W2 + b2  (engine A)
    { GemmP p{}; p.A=gbuf; p.ldA=DFF_; p.B=W2T+(long)l*DD*DFF_; p.ldB=DFF_;
      p.outF=hbuf; p.ldO=DD; p.bias=b2+l*DD;
      p.residF=hbuf; p.ldR=DD; p.K=DFF_;
      launch_gemmA(p, BS, DD, 1, stream); }
    hin=hbuf;
  }
  ln_k<<<dim3(BS),dim3(256),0,stream>>>(hbuf, lnf_g, lnf_b, out, (unsigned short*)nullptr, (const float*)nullptr);
}

// Round 14
// 1951.652 us; speedup vs baseline: 1.0577x; 1.0150x over previous
//
#include <hip/hip_runtime.h>
#include <hip/hip_bf16.h>
#include <stdint.h>

#define LL 6
#define DD 1024
#define HH 16
#define DKK 64
#define SS 512
#define BB 8
#define DFF_ 4096
#define BS (BB*SS)
#define NEGV -1.0e9f

typedef __attribute__((ext_vector_type(8))) short short8;
typedef __attribute__((ext_vector_type(4))) float f32x4;
typedef __attribute__((ext_vector_type(4))) unsigned short ushort4v;

static __device__ __forceinline__ float bf2f(unsigned short u){
  union { unsigned int i; float f; } v; v.i = ((unsigned int)u)<<16; return v.f;
}
static __device__ __forceinline__ unsigned short f2bf(float f){
  union { float f; unsigned int i; } v; v.f=f;
  unsigned int r = v.i + 0x7fff + ((v.i>>16)&1);   // RNE
  return (unsigned short)(r>>16);
}

static __device__ __forceinline__ void gload16(const void* g, void* l){
  __builtin_amdgcn_global_load_lds((const __attribute__((address_space(1))) unsigned int*)g,
                                   (__attribute__((address_space(3))) unsigned int*)l, 16, 0, 0);
}

// ---------------- multi-descriptor fp32->bf16 transpose: out[c][r] = in[r][c] ----------------
struct TrDesc { const float* in; unsigned short* out; long is1,is2,os1,os2; int ldin,ldout,zd,gx,gy; };
struct TrPack { TrDesc d[7]; int cum[8]; };

__global__ void __launch_bounds__(256) tr_multi_k(TrPack P)
{
  __shared__ float t[32][33];
  int bid=blockIdx.x, di=0;
  #pragma unroll
  for(int k=1;k<7;k++) if(bid>=P.cum[k]) di=k;
  TrDesc dd=P.d[di];
  int local=bid-P.cum[di];
  int bx=local%dd.gx; int rest=local/dd.gx;
  int by=rest%dd.gy; int z=rest/dd.gy;
  int z1=z/dd.zd, z2=z%dd.zd;
  const float* ip=dd.in+z1*dd.is1+z2*dd.is2;
  unsigned short* op=dd.out+z1*dd.os1+z2*dd.os2;
  int r0=by*32, c0=bx*32;
  int tx=threadIdx.x, ty=threadIdx.y;
  #pragma unroll
  for(int i=0;i<4;i++)
    t[ty+i*8][tx] = ip[(long)(r0+ty+i*8)*dd.ldin + c0+tx];
  __syncthreads();
  #pragma unroll
  for(int i=0;i<4;i++)
    op[(long)(c0+ty+i*8)*dd.ldout + r0+tx] = f2bf(t[tx][ty+i*8]);
}

// ---------------- mask bit-pack ----------------
__global__ void __launch_bounds__(256) maskpack_k(const int* __restrict__ mask, unsigned* __restrict__ mb)
{
  int idx = blockIdx.x*256 + threadIdx.x;     // idx = row*16 + w
  int row = idx>>4, w = idx&15;
  const int* mp = mask + (long)row*SS + w*32;
  unsigned v=0;
  #pragma unroll
  for(int i=0;i<32;i++) v |= (mp[i]!=0) ? (1u<<i) : 0u;
  mb[idx]=v;
}

// ---------------- LayerNorm: out = LN(src)*g+b (+resid); fp32 and/or bf16 out ----------------
__global__ void __launch_bounds__(256) ln_k(const float* __restrict__ src,
    const float* __restrict__ gw, const float* __restrict__ bw,
    float* __restrict__ outf, unsigned short* __restrict__ outb,
    const float* __restrict__ resid)
{
  long row=blockIdx.x;
  float4 v=((const float4*)(src+row*DD))[threadIdx.x];
  float s=v.x+v.y+v.z+v.w;
  float s2=v.x*v.x+v.y*v.y+v.z*v.z+v.w*v.w;
  #pragma unroll
  for(int o=32;o;o>>=1){ s+=__shfl_xor(s,o); s2+=__shfl_xor(s2,o); }
  __shared__ float red[8];
  int wid=threadIdx.x>>6, lane=threadIdx.x&63;
  if(lane==0){ red[wid]=s; red[4+wid]=s2; }
  __syncthreads();
  s=red[0]+red[1]+red[2]+red[3];
  s2=red[4]+red[5]+red[6]+red[7];
  float mu=s*(1.f/DD);
  float rstd=rsqrtf(s2*(1.f/DD)-mu*mu+1e-5f);
  int c=threadIdx.x*4;
  float4 g4=*(const float4*)(gw+c), b4=*(const float4*)(bw+c);
  float4 o;
  o.x=(v.x-mu)*rstd*g4.x+b4.x;
  o.y=(v.y-mu)*rstd*g4.y+b4.y;
  o.z=(v.z-mu)*rstd*g4.z+b4.z;
  o.w=(v.w-mu)*rstd*g4.w+b4.w;
  if(resid){
    float4 r4=((const float4*)(resid+row*DD))[threadIdx.x];
    o.x+=r4.x; o.y+=r4.y; o.z+=r4.z; o.w+=r4.w;
  }
  if(outf) ((float4*)(outf+row*DD))[threadIdx.x]=o;
  if(outb){
    uint2 pk;
    pk.x=(unsigned)f2bf(o.x)|((unsigned)f2bf(o.y)<<16);
    pk.y=(unsigned)f2bf(o.z)|((unsigned)f2bf(o.w)<<16);
    ((uint2*)(outb+row*DD))[threadIdx.x]=pk;
  }
}

// ------- fused: t = LN(srcb bf16; g2,b2)+resid -> outf;  LN(t; g1,b1) -> outb bf16 -------
__global__ void __launch_bounds__(256) ln2_k(const unsigned short* __restrict__ srcb,
    const float* __restrict__ resid,
    const float* __restrict__ g2, const float* __restrict__ b2,
    const float* __restrict__ g1, const float* __restrict__ b1,
    float* __restrict__ outf, unsigned short* __restrict__ outb)
{
  long row=blockIdx.x;
  int wid=threadIdx.x>>6, lane=threadIdx.x&63, c=threadIdx.x*4;
  __shared__ float red[8];
  uint2 pin=((const uint2*)(srcb+row*DD))[threadIdx.x];
  float4 v;
  v.x=bf2f((unsigned short)(pin.x&0xffff));
  v.y=bf2f((unsigned short)(pin.x>>16));
  v.z=bf2f((unsigned short)(pin.y&0xffff));
  v.w=bf2f((unsigned short)(pin.y>>16));
  float s=v.x+v.y+v.z+v.w;
  float s2=v.x*v.x+v.y*v.y+v.z*v.z+v.w*v.w;
  #pragma unroll
  for(int o=32;o;o>>=1){ s+=__shfl_xor(s,o); s2+=__shfl_xor(s2,o); }
  if(lane==0){ red[wid]=s; red[4+wid]=s2; }
  __syncthreads();
  s=red[0]+red[1]+red[2]+red[3];
  s2=red[4]+red[5]+red[6]+red[7];
  float mu=s*(1.f/DD);
  float rstd=rsqrtf(s2*(1.f/DD)-mu*mu+1e-5f);
  float4 g4=*(const float4*)(g2+c), b4=*(const float4*)(b2+c);
  float4 r4=((const float4*)(resid+row*DD))[threadIdx.x];
  float4 o;
  o.x=(v.x-mu)*rstd*g4.x+b4.x+r4.x;
  o.y=(v.y-mu)*rstd*g4.y+b4.y+r4.y;
  o.z=(v.z-mu)*rstd*g4.z+b4.z+r4.z;
  o.w=(v.w-mu)*rstd*g4.w+b4.w+r4.w;
  ((float4*)(outf+row*DD))[threadIdx.x]=o;
  s=o.x+o.y+o.z+o.w;
  s2=o.x*o.x+o.y*o.y+o.z*o.z+o.w*o.w;
  #pragma unroll
  for(int of=32;of;of>>=1){ s+=__shfl_xor(s,of); s2+=__shfl_xor(s2,of); }
  __syncthreads();
  if(lane==0){ red[wid]=s; red[4+wid]=s2; }
  __syncthreads();
  s=red[0]+red[1]+red[2]+red[3];
  s2=red[4]+red[5]+red[6]+red[7];
  mu=s*(1.f/DD);
  rstd=rsqrtf(s2*(1.f/DD)-mu*mu+1e-5f);
  g4=*(const float4*)(g1+c); b4=*(const float4*)(b1+c);
  uint2 pk;
  pk.x=(unsigned)f2bf((o.x-mu)*rstd*g4.x+b4.x)|((unsigned)f2bf((o.y-mu)*rstd*g4.y+b4.y)<<16);
  pk.y=(unsigned)f2bf((o.z-mu)*rstd*g4.z+b4.z)|((unsigned)f2bf((o.w-mu)*rstd*g4.w+b4.w)<<16);
  ((uint2*)(outb+row*DD))[threadIdx.x]=pk;
}

// ---------------- GEMM params ----------------
struct GemmP {
  const unsigned short* A; long sA1; int ldA;
  const unsigned short* B; long sB1; int ldB;
  float* outF; unsigned short* outB; long sO1; int ldO;
  const float* bias;
  const float* residF; int ldR;
  const unsigned short* residB;
  unsigned short *kt, *vt;
  int K, relu, mb;
};

// XCD-bijective m-major block remap (requires gridDim.x % 8 == 0)
static __device__ __forceinline__ void xcd_map(int mb,int BM,int BN,int& m0,int& n0){
  const int nwg=gridDim.x, bid=blockIdx.x;
  const int nb=(bid&7)*(nwg>>3)+(bid>>3);
  m0=(nb%mb)*BM; n0=(nb/mb)*BN;
}

// ---------------- engine A: 128x128, 8 waves (wt 64x32), BK=64, 4 LDS buffers,
//   pair-unroll (2 K-tiles per barrier, stage issue split across halves),
//   __syncthreads full-drain, both-sides swizzle ----------------
__global__ void __launch_bounds__(512,2) gemmA_k(GemmP p)
{
  constexpr int BM=128, BN=128, BK=64;
  constexpr int BUFE=(BM+BN)*BK;
  constexpr int FN=2;
  constexpr int WNT=32;
  __shared__ __align__(16) unsigned short smem[4*BUFE];   // 128 KB
  const int tid=threadIdx.x, lane=tid&63, wid=tid>>6;
  const int wr=wid>>2, wc=wid&3;
  const int lr=lane&15, lk=(lane>>4)*8;
  int m0,n0; xcd_map(p.mb,BM,BN,m0,n0);
  const int z=blockIdx.y;
  const unsigned short* Ap=p.A+(long)z*p.sA1;
  const unsigned short* Bp=p.B+(long)z*p.sB1;
  const int NT=p.K/BK;

  const int sr8 = lane>>3;
  const int scol = ((lane&7) ^ sr8) << 3;

  #define STAGEA(T,BI) { \
    const long kb_=(long)(T)*BK; \
    unsigned short* As_=smem+(BI)*BUFE; \
    unsigned short* Bs_=As_+BM*BK; \
    _Pragma("unroll") \
    for(int L=0;L<2;L++){ \
      int r_=L*64+wid*8+sr8; \
      gload16(Ap+(long)(m0+r_)*p.ldA+kb_+scol, As_+L*4096+wid*512); \
    } \
    _Pragma("unroll") \
    for(int L=0;L<2;L++){ \
      int r_=L*64+wid*8+sr8; \
      gload16(Bp+(long)(n0+r_)*p.ldB+kb_+scol, Bs_+L*4096+wid*512); \
    } }

  f32x4 acc[4][FN];
  #pragma unroll
  for(int m=0;m<4;m++)
    #pragma unroll
    for(int n=0;n<FN;n++) acc[m][n]=(f32x4){0.f,0.f,0.f,0.f};

  STAGEA(0,0);
  STAGEA(1,1);
  __syncthreads();

  const int xr = (lr&7)<<3;
  for(int t=0;t<NT;t+=2){
    if(t+2<NT) STAGEA(t+2,(t+2)&3);              // issue half the prefetch now...
    #pragma unroll
    for(int u=0;u<2;u++){
      const unsigned short* As=smem+((t+u)&3)*BUFE;
      const unsigned short* Bs=As+BM*BK;
      #pragma unroll
      for(int kk=0;kk<2;kk++){
        short8 a[4], b[FN];
        #pragma unroll
        for(int m=0;m<4;m++)
          a[m]=*(const short8*)(As + (wr*64+m*16+lr)*BK + ((kk*32+lk)^xr));
        #pragma unroll
        for(int n=0;n<FN;n++)
          b[n]=*(const short8*)(Bs + (wc*WNT+n*16+lr)*BK + ((kk*32+lk)^xr));
        __builtin_amdgcn_s_setprio(1);
        #pragma unroll
        for(int m=0;m<4;m++)
          #pragma unroll
          for(int n=0;n<FN;n++)
            acc[m][n]=__builtin_amdgcn_mfma_f32_16x16x32_bf16(a[m],b[n],acc[m][n],0,0,0);
        __builtin_amdgcn_s_setprio(0);
      }
      if(u==0 && t+3<NT) STAGEA(t+3,(t+3)&3);    // ...and the other half mid-compute
    }
    __syncthreads();                             // full drain: t+2,t+3 resident after this
  }
  #undef STAGEA

  const int rl=(lane>>4)*4;
  #pragma unroll
  for(int m=0;m<4;m++){
    int gr0 = m0 + wr*64 + m*16 + rl;
    #pragma unroll
    for(int n=0;n<FN;n++){
      int gc = n0 + wc*WNT + n*16 + lr;
      float bv = p.bias ? p.bias[gc] : 0.f;
      #pragma unroll
      for(int r=0;r<4;r++){
        long ro=(long)(gr0+r);
        float val=acc[m][n][r]+bv;
        if(p.relu) val=fmaxf(val,0.f);
        if(p.residF) val += p.residF[ro*(long)p.ldR+gc];
        if(p.residB) val += bf2f(p.residB[ro*(long)p.ldR+gc]);
        long oo = (long)z*p.sO1 + ro*(long)p.ldO+gc;
        if(p.outF) p.outF[oo]=val;
        if(p.outB) p.outB[oo]=f2bf(val);
      }
    }
  }
}

static inline void launch_gemmA(GemmP& p,int M,int N,int Z,hipStream_t s){
  p.mb=M/128;
  gemmA_k<<<dim3((M/128)*(N/128),Z),dim3(512),0,s>>>(p);
}

// ---------------- engine B: 256x256, 8 waves (wave tile 128x64), BK=64,
//   2 LDS buffers (128KB), issue-early staging split A-half/B-half,
//   __syncthreads full-drain, both-sides swizzle, setprio ----------------
template<int MODE>
__global__ void __launch_bounds__(512,1) gemmB_k(GemmP p)
{
  constexpr int BM=256, BN=256, BK=64;
  constexpr int BUFE=(BM+BN)*BK;                 // 32768 elems (64 KB)
  __shared__ __align__(16) unsigned short smem[2*BUFE];   // 128 KB
  const int tid=threadIdx.x, lane=tid&63, wid=tid>>6;
  const int wr=wid>>2, wc=wid&3;                 // 2M x 4N waves, wave tile 128x64
  const int lr=lane&15, lk=(lane>>4)*8;
  int m0,n0; xcd_map(p.mb,BM,BN,m0,n0);
  const unsigned short* Ap=p.A;
  const unsigned short* Bp=p.B;
  const int NT=p.K/BK;

  const int sr8 = lane>>3;
  const int scol = ((lane&7) ^ sr8) << 3;

  #define STAGEB_A(T,BI) { \
    const long kb_=(long)(T)*BK; \
    unsigned short* As_=smem+(BI)*BUFE; \
    _Pragma("unroll") \
    for(int L=0;L<4;L++){ \
      int r_=L*64+wid*8+sr8; \
      gload16(Ap+(long)(m0+r_)*p.ldA+kb_+scol, As_+L*4096+wid*512); \
    } }
  #define STAGEB_B(T,BI) { \
    const long kb_=(long)(T)*BK; \
    unsigned short* Bs_=smem+(BI)*BUFE+BM*BK; \
    _Pragma("unroll") \
    for(int L=0;L<4;L++){ \
      int r_=L*64+wid*8+sr8; \
      gload16(Bp+(long)(n0+r_)*p.ldB+kb_+scol, Bs_+L*4096+wid*512); \
    } }

  f32x4 acc[8][4];
  #pragma unroll
  for(int m=0;m<8;m++)
    #pragma unroll
    for(int n=0;n<4;n++) acc[m][n]=(f32x4){0.f,0.f,0.f,0.f};

  STAGEB_A(0,0);
  STAGEB_B(0,0);
  __syncthreads();

  const int xr = (lr&7)<<3;
  for(int t=0;t<NT;t++){
    if(t+1<NT) STAGEB_A(t+1,(t+1)&1);            // A-half now, B-half mid-compute
    const unsigned short* As=smem+(t&1)*BUFE;
    const unsigned short* Bs=As+BM*BK;
    #pragma unroll
    for(int kk=0;kk<2;kk++){
      short8 a[8], b[4];
      #pragma unroll
      for(int m=0;m<8;m++)
        a[m]=*(const short8*)(As + (wr*128+m*16+lr)*BK + ((kk*32+lk)^xr));
      #pragma unroll
      for(int n=0;n<4;n++)
        b[n]=*(const short8*)(Bs + (wc*64+n*16+lr)*BK + ((kk*32+lk)^xr));
      __builtin_amdgcn_s_setprio(1);
      #pragma unroll
      for(int m=0;m<8;m++)
        #pragma unroll
        for(int n=0;n<4;n++)
          acc[m][n]=__builtin_amdgcn_mfma_f32_16x16x32_bf16(a[m],b[n],acc[m][n],0,0,0);
      __builtin_amdgcn_s_setprio(0);
      if(kk==0 && t+1<NT) STAGEB_B(t+1,(t+1)&1);
    }
    __syncthreads();
  }
  #undef STAGEB_A
  #undef STAGEB_B

  const int rl=(lane>>4)*4;
  if(MODE==1){
    int sec = n0>>10;    // 0=Q,1=K,2=V (tiles never straddle 1024 boundaries)
    #pragma unroll
    for(int m=0;m<8;m++){
      int gr0 = m0 + wr*128 + m*16 + rl;
      int b = gr0>>9, s0 = gr0&511;
      #pragma unroll
      for(int n=0;n<4;n++){
        int gc = n0 + wc*64 + n*16 + lr;
        if(sec==0){
          #pragma unroll
          for(int r=0;r<4;r++)
            p.outB[(long)(gr0+r)*1024 + gc] = f2bf(acc[m][n][r]);
        } else {
          unsigned short* dst = sec==1 ? p.kt : p.vt;
          int hh=(gc>>6)&15, d=gc&63;
          ushort4v pk;
          pk.x=f2bf(acc[m][n][0]); pk.y=f2bf(acc[m][n][1]);
          pk.z=f2bf(acc[m][n][2]); pk.w=f2bf(acc[m][n][3]);
          *(ushort4v*)(dst + (((long)b*HH+hh)*DKK+d)*SS + s0) = pk;
        }
      }
    }
  } else {
    #pragma unroll
    for(int m=0;m<8;m++){
      int gr0 = m0 + wr*128 + m*16 + rl;
      #pragma unroll
      for(int n=0;n<4;n++){
        int gc = n0 + wc*64 + n*16 + lr;
        float bv = p.bias ? p.bias[gc] : 0.f;
        #pragma unroll
        for(int r=0;r<4;r++){
          long ro=(long)(gr0+r);
          float val=acc[m][n][r]+bv;
          if(p.relu) val=fmaxf(val,0.f);
          if(p.residF) val += p.residF[ro*(long)p.ldR+gc];
          if(p.residB) val += bf2f(p.residB[ro*(long)p.ldR+gc]);
          long oo = ro*(long)p.ldO+gc;
          if(p.outF) p.outF[oo]=val;
          if(p.outB) p.outB[oo]=f2bf(val);
        }
      }
    }
  }
}

template<int MODE>
static inline void launch_gemmB(GemmP& p,int M,int N,hipStream_t s){
  p.mb=M/256;
  gemmB_k<MODE><<<dim3((M/256)*(N/256)),dim3(512),0,s>>>(p);
}

// ------- fused attention: S = Q·KRT^T -> mask/scale/softmax -> p fp32 (d_out)
//         then PV in-kernel: att = p @ V -> attb bf16 -------
__global__ void __launch_bounds__(512) att_k(const unsigned short* __restrict__ Qb,
    const unsigned short* __restrict__ KRT, float* __restrict__ pout,
    const unsigned* __restrict__ maskb, const unsigned short* __restrict__ Vt,
    unsigned short* __restrict__ attb)
{
  constexpr int BM=128, BK=32, NT=512;
  constexpr int FM=4, FN=8;                    // QK: 8 waves = 2M x 4N, wave tile 64x128
  __shared__ __align__(16) char smem[49152];
  unsigned short* As = (unsigned short*)smem;            // 8KB  [128*32]
  unsigned short* Bs = (unsigned short*)(smem+8192);     // 32KB [512*32]
  unsigned short* Ps = (unsigned short*)smem;            // 32KB [128*128]  (aliases As/Bs, QK-dead)
  unsigned short* Vs = (unsigned short*)(smem+32768);    // 16KB [64*128]   (aliases Bs tail)
  __shared__ float redmx[BM][4];
  __shared__ float redsm[BM][4];
  int bh = blockIdx.y; int b = bh>>4, h = bh&15;
  const unsigned short* Ap = Qb + (long)b*SS*1024 + h*64;     // Q
  const unsigned short* Bp = KRT + (long)b*SS*1024 + h*64;    // KRT rows (ld 1024)
  int m0 = blockIdx.x*BM;
  int tid=threadIdx.x, lane=tid&63, wid=tid>>6;
  int wr=wid>>2, wc=wid&3;
  f32x4 acc[FM][FN];
  #pragma unroll
  for(int i=0;i<FM;i++)
    #pragma unroll
    for(int j=0;j<FN;j++) acc[i][j]=(f32x4){0.f,0.f,0.f,0.f};
  const int lr=lane&15, lk=(lane>>4)*8;
  for(int k0=0;k0<DKK;k0+=BK){
    { int v=tid;
      gload16(Ap + (long)(m0+(v>>2))*1024 + k0 + (v&3)*8, As + (wid*64)*8); }
    #pragma unroll
    for(int r=0;r<4;r++){
      int v=r*NT+tid;
      gload16(Bp + (long)(v>>2)*1024 + k0 + (v&3)*8, Bs + (r*NT+wid*64)*8);
    }
    __syncthreads();
    short8 af[FM], bfr[FN];
    #pragma unroll
    for(int i=0;i<FM;i++) af[i]=*(const short8*)(As + (wr*64+i*16+lr)*BK + lk);
    #pragma unroll
    for(int j=0;j<FN;j++) bfr[j]=*(const short8*)(Bs + (wc*128+j*16+lr)*BK + lk);
    #pragma unroll
    for(int i=0;i<FM;i++)
      #pragma unroll
      for(int j=0;j<FN;j++)
        acc[i][j]=__builtin_amdgcn_mfma_f32_16x16x32_bf16(af[i],bfr[j],acc[i][j],0,0,0);
    __syncthreads();
  }
  const int rl=(lane>>4)*4;
  // mask (bit-packed) + scale + per-row max
  #pragma unroll
  for(int i=0;i<FM;i++){
    #pragma unroll
    for(int r=0;r<4;r++){
      int row=wr*64+i*16+rl+r;
      uint4 mw = *((const uint4*)(maskb + ((long)(b*SS+m0+row))*16 + wc*4));
      float m_=-3.4e38f;
      #pragma unroll
      for(int j=0;j<FN;j++){
        unsigned word = (j>>1)==0? mw.x : (j>>1)==1? mw.y : (j>>1)==2? mw.z : mw.w;
        float v = ((word>>(((j&1)<<4)+lr))&1) ? NEGV : acc[i][j][r]*0.125f;
        acc[i][j][r]=v; m_=fmaxf(m_,v);
      }
      #pragma unroll
      for(int o=1;o<16;o<<=1) m_=fmaxf(m_,__shfl_xor(m_,o));
      if(lr==0) redmx[row][wc]=m_;
    }
  }
  __syncthreads();
  #pragma unroll
  for(int i=0;i<FM;i++){
    #pragma unroll
    for(int r=0;r<4;r++){
      int row=wr*64+i*16+rl+r;
      float m_=fmaxf(fmaxf(redmx[row][0],redmx[row][1]),fmaxf(redmx[row][2],redmx[row][3]));
      float s_=0.f;
      #pragma unroll
      for(int j=0;j<FN;j++){
        float e=__expf(acc[i][j][r]-m_);
        acc[i][j][r]=e; s_+=e;
      }
      #pragma unroll
      for(int o=1;o<16;o<<=1) s_+=__shfl_xor(s_,o);
      if(lr==0) redsm[row][wc]=s_;
    }
  }
  __syncthreads();
  // normalize + write p fp32 (attns output)
  #pragma unroll
  for(int i=0;i<FM;i++){
    #pragma unroll
    for(int r=0;r<4;r++){
      int row=wr*64+i*16+rl+r;
      float inv=1.f/(redsm[row][0]+redsm[row][1]+redsm[row][2]+redsm[row][3]);
      long obase=((long)bh*SS + m0+row)*(long)SS;
      #pragma unroll
      for(int j=0;j<FN;j++){
        int col=wc*128+j*16+lr;
        float pv=acc[i][j][r]*inv;
        acc[i][j][r]=pv;
        pout[obase+col]=pv;
      }
    }
  }
  __syncthreads();   // QK-phase LDS fully dead before Ps/Vs staging
  // ---- PV: att[128,64] = p[128,512] @ V[512,64], K-chunks of 128 ----
  f32x4 attacc[4];
  #pragma unroll
  for(int j=0;j<4;j++) attacc[j]=(f32x4){0.f,0.f,0.f,0.f};
  for(int kc=0;kc<4;kc++){
    // stage V chunk [64 d][128 k] from Vt, source pre-swizzled (read-XOR = (d&7)<<3 elems)
    #pragma unroll
    for(int r2=0;r2<2;r2++){
      int v=r2*512+tid;
      int d=v>>4, m=v&15;
      int u=m^(d&7);
      gload16(Vt + ((long)bh*64 + d)*512 + kc*128 + u*8, Vs + (r2*512 + wid*64)*8);
    }
    // stage P chunk from acc (only waves owning this 128-col chunk)
    if(wc==kc){
      #pragma unroll
      for(int i=0;i<FM;i++){
        #pragma unroll
        for(int r=0;r<4;r++){
          int row=wr*64+i*16+rl+r;
          #pragma unroll
          for(int j=0;j<FN;j++){
            int col=j*16+lr;
            Ps[row*128 + (col ^ ((row&7)<<3))] = f2bf(acc[i][j][r]);
          }
        }
      }
    }
    __syncthreads();
    #pragma unroll
    for(int kk=0;kk<4;kk++){
      int arow=wid*16+lr;
      short8 paf=*(const short8*)(Ps + arow*128 + ((kk*32+lk) ^ ((arow&7)<<3)));
      #pragma unroll
      for(int j=0;j<4;j++){
        int d=j*16+lr;
        short8 vbf=*(const short8*)(Vs + d*128 + ((kk*32+lk) ^ ((d&7)<<3)));
        attacc[j]=__builtin_amdgcn_mfma_f32_16x16x32_bf16(paf,vbf,attacc[j],0,0,0);
      }
    }
    __syncthreads();
  }
  // epilogue: attb[(b*S + row)][h*64 + d]
  #pragma unroll
  for(int j=0;j<4;j++){
    #pragma unroll
    for(int r=0;r<4;r++){
      int row = m0 + wid*16 + rl + r;
      attb[((long)b*SS + row)*DD + h*64 + j*16 + lr] = f2bf(attacc[j][r]);
    }
  }
}

extern "C" void kernel_launch(void* const* d_in, const int* in_sizes, int n_in,
                              void* d_out, int out_size, void* d_ws, size_t ws_size,
                              hipStream_t stream)
{
  const float* x    =(const float*)d_in[0];
  const int*   mask =(const int*)d_in[1];
  const float* rel  =(const float*)d_in[2];
  const float* Wq   =(const float*)d_in[3];
  const float* Wk   =(const float*)d_in[4];
  const float* Wv   =(const float*)d_in[5];
  const float* Wo   =(const float*)d_in[6];
  const float* bo   =(const float*)d_in[7];
  const float* ln_g =(const float*)d_in[8];
  const float* ln_b =(const float*)d_in[9];
  const float* ln2_g=(const float*)d_in[10];
  const float* ln2_b=(const float*)d_in[11];
  const float* W1   =(const float*)d_in[12];
  const float* b1   =(const float*)d_in[13];
  const float* W2   =(const float*)d_in[14];
  const float* b2   =(const float*)d_in[15];
  const float* lnf_g=(const float*)d_in[16];
  const float* lnf_b=(const float*)d_in[17];
  float* out=(float*)d_out;

  char* w=(char*)d_ws;
  auto alloc=[&](long bytes)->void*{ void* p=(void*)w; w += (bytes+255)&~255L; return p; };
  unsigned short* WTqkv=(unsigned short*)alloc((long)LL*3072*1024*2);
  unsigned short* WoT  =(unsigned short*)alloc((long)LL*1024*1024*2);
  unsigned short* W1T  =(unsigned short*)alloc((long)LL*DFF_*DD*2);
  unsigned short* W2T  =(unsigned short*)alloc((long)LL*DD*DFF_*2);
  unsigned short* relT =(unsigned short*)alloc((long)BB*SS*SS*2);
  unsigned short* qin_b=(unsigned short*)alloc((long)BS*DD*2);
  unsigned short* Qb   =(unsigned short*)alloc((long)BS*1024*2);
  unsigned short* Vt   =(unsigned short*)alloc((long)BB*HH*DKK*SS*2);
  unsigned short* Kt   =(unsigned short*)alloc((long)BB*HH*DKK*SS*2);
  unsigned short* KRT  =(unsigned short*)alloc((long)BB*SS*1024*2);
  unsigned short* attb =(unsigned short*)alloc((long)BS*DD*2);
  unsigned short* attres=(unsigned short*)alloc((long)BS*DD*2);
  unsigned short* gbuf =(unsigned short*)alloc((long)BS*DFF_*2);
  float*          hbuf =(float*)alloc((long)BS*DD*4);
  unsigned*       maskb=(unsigned*)alloc((long)BS*16*4);
  (void)ws_size; (void)in_sizes; (void)n_in; (void)out_size;

  // single setup launch: all weight transposes + relation transpose
  TrPack tp;
  auto set=[&](int i, const float* in, unsigned short* o, int ldin, int ldout,
               long is1, long os1, int zd, long is2, long os2, int gx, int gy){
    tp.d[i]={in,o,is1,is2,os1,os2,ldin,ldout,zd,gx,gy};
  };
  set(0, Wq, WTqkv,           1024,1024,(long)1024*1024,(long)3072*1024,1,0,0, 32,32);
  set(1, Wk, WTqkv+1024*1024, 1024,1024,(long)1024*1024,(long)3072*1024,1,0,0, 32,32);
  set(2, Wv, WTqkv+2048*1024, 1024,1024,(long)1024*1024,(long)3072*1024,1,0,0, 32,32);
  set(3, Wo, WoT,             1024,1024,(long)1024*1024,(long)1024*1024,1,0,0, 32,32);
  set(4, W1, W1T, 4096,1024,(long)1024*4096,(long)1024*4096,1,0,0, 128,32);
  set(5, W2, W2T, 1024,4096,(long)4096*1024,(long)4096*1024,1,0,0, 32,128);
  set(6, rel, relT, 512,512,(long)512*512,(long)512*512,1,0,0, 16,16);
  int nb[7]={32*32*LL,32*32*LL,32*32*LL,32*32*LL,128*32*LL,32*128*LL,16*16*BB};
  tp.cum[0]=0;
  for(int i=0;i<7;i++) tp.cum[i+1]=tp.cum[i]+nb[i];
  tr_multi_k<<<dim3(tp.cum[7]),dim3(32,8),0,stream>>>(tp);
  maskpack_k<<<dim3(BS*16/256),dim3(256),0,stream>>>(mask, maskb);

  const float* hin = x;
  for(int l=0;l<LL;l++){
    // q_in = LN(h) -> bf16
    ln_k<<<dim3(BS),dim3(256),0,stream>>>(hin, ln_g+l*DD, ln_b+l*DD, (float*)nullptr, qin_b, (const float*)nullptr);
    // QKV = q_in @ [Wq|Wk|Wv]  (engine B, 256^2); epilogue: Qb + Kt/Vt transposed
    { GemmP p{}; p.A=qin_b; p.ldA=DD; p.B=WTqkv+(long)l*3072*1024; p.ldB=DD;
      p.outB=Qb; p.kt=Kt; p.vt=Vt; p.K=DD;
      launch_gemmB<1>(p, BS, 3072, stream); }
    // KRT[b][n][h*64+d] = sum_k rel[k,n] K[k,hd]  (8 batched GEMMs, engine A)
    { GemmP p{}; p.A=relT; p.sA1=(long)SS*SS; p.ldA=SS;
      p.B=Kt; p.sB1=(long)HH*DKK*SS; p.ldB=SS;
      p.outB=KRT; p.sO1=(long)SS*1024; p.ldO=1024; p.K=SS;
      launch_gemmA(p, SS, 1024, BB, stream); }
    // fused scores+softmax+PV
    float* attn_l = out + (long)BS*DD + (long)l*BB*HH*SS*SS;
    att_k<<<dim3(SS/128, BB*HH),dim3(512),0,stream>>>(Qb, KRT, attn_l, maskb, Vt, attb);
    // attres(bf16) = att @ Wo + bo + q_in(bf16)  (engine A)
    { GemmP p{}; p.A=attb; p.ldA=DD; p.B=WoT+(long)l*1024*1024; p.ldB=DD;
      p.outB=attres; p.ldO=DD; p.bias=bo+l*DD;
      p.residB=qin_b; p.ldR=DD; p.K=DD;
      launch_gemmA(p, BS, DD, 1, stream); }
    // h = hin + LN2(attres) -> hbuf ; f = LN1(h) -> qin_b
    ln2_k<<<dim3(BS),dim3(256),0,stream>>>(attres, hin, ln2_g+l*DD, ln2_b+l*DD,
        ln_g+l*DD, ln_b+l*DD, hbuf, qin_b);
    // g = relu(f @ W1 + b1)  (engine B, 256^2)
    { GemmP p{}; p.A=qin_b; p.ldA=DD; p.B=W1T+(long)l*DFF_*DD; p.ldB=DD;
      p.outB=gbuf; p.ldO=DFF_; p.bias=b1+l*DFF_; p.relu=1; p.K=DD;
      launch_gemmB<0>(p, BS, DFF_, stream); }
    // h += g @ W2 + b2  (engine A)
    { GemmP p{}; p.A=gbuf; p.ldA=DFF_; p.B=W2T+(long)l*DD*DFF_; p.ldB=DFF_;
      p.outF=hbuf; p.ldO=DD; p.bias=b2+l*DD;
      p.residF=hbuf; p.ldR=DD; p.K=DFF_;
      launch_gemmA(p, BS, DD, 1, stream); }
    hin=hbuf;
  }
  ln_k<<<dim3(BS),dim3(256),0,stream>>>(hbuf, lnf_g, lnf_b, out, (unsigned short*)nullptr, (const float*)nullptr);
}